// Round 4
// baseline (1709.510 us; speedup 1.0000x reference)
//
#include <hip/hip_runtime.h>

// ---------------------------------------------------------------------------
// GCN forward: 3x GCNConv(+relu) -> global_mean_pool -> fc -> log_softmax
// N=100000 nodes, E=3200000 edges, G=512 graphs, feats 128->64->128->64
// R3: two-level binned CSR build (bucket by dst>>6, then in-LDS exact sort)
// replaces the global atomic counting sort (write amplification 16x -> ~1x).
// GEMM: register-blocked tiles. Aggregation: CSR gather, no atomics.
// ---------------------------------------------------------------------------

static inline int grid_for(long long total, int block) {
    return (int)((total + block - 1) / block);
}

// --- binned CSR build ------------------------------------------------------
__global__ void k_zero_int(int* p, int n) {
    int i = blockIdx.x * blockDim.x + threadIdx.x;
    if (i < n) p[i] = 0;
}

__global__ void k_bucket_count(const int* __restrict__ dst, int* __restrict__ bcnt, int E) {
    int i = blockIdx.x * blockDim.x + threadIdx.x;
    if (i < E) atomicAdd(&bcnt[dst[i] >> 6], 1);
}

// single-block exclusive scan over bucket counts; also seeds bcur.
__global__ void k_bucket_scan(const int* __restrict__ bcnt, int* __restrict__ bbase,
                              int* __restrict__ bcur, int nbuk, int E) {
    __shared__ int s[256];
    __shared__ int carry;
    if (threadIdx.x == 0) carry = 0;
    __syncthreads();
    for (int base = 0; base < nbuk; base += 256) {
        int i = base + threadIdx.x;
        int v = (i < nbuk) ? bcnt[i] : 0;
        s[threadIdx.x] = v;
        __syncthreads();
        for (int off = 1; off < 256; off <<= 1) {
            int t = (threadIdx.x >= (unsigned)off) ? s[threadIdx.x - off] : 0;
            __syncthreads();
            s[threadIdx.x] += t;
            __syncthreads();
        }
        int excl = s[threadIdx.x] - v + carry;
        if (i < nbuk) { bbase[i] = excl; bcur[i] = excl; }
        __syncthreads();
        if (threadIdx.x == 255) carry += s[255];
        __syncthreads();
    }
    if (threadIdx.x == 0) bbase[nbuk] = E;
}

// append (src,dst) to its dst-bucket region (sequential within bucket -> ~1x WA)
__global__ void k_bin(const int* __restrict__ src, const int* __restrict__ dst,
                      int* __restrict__ bcur, int2* __restrict__ pairs, int E) {
    int i = blockIdx.x * blockDim.x + threadIdx.x;
    if (i >= E) return;
    int d = dst[i];
    int pos = atomicAdd(&bcur[d >> 6], 1);
    pairs[pos] = make_int2(src[i], d);
}

// one block per bucket: exact in-LDS sort by dst, emit srt/counts/rowoff/dinv
__global__ __launch_bounds__(256) void k_bucket_csr(const int2* __restrict__ pairs,
                                                    const int* __restrict__ bbase,
                                                    int* __restrict__ srt,
                                                    int* __restrict__ counts,
                                                    int* __restrict__ rowoff,
                                                    float* __restrict__ dinv, int N) {
    int b = blockIdx.x;
    int base = bbase[b], end = bbase[b + 1];
    __shared__ int hist[64];
    __shared__ int loff[64];
    if (threadIdx.x < 64) hist[threadIdx.x] = 0;
    __syncthreads();
    for (int i = base + (int)threadIdx.x; i < end; i += 256)
        atomicAdd(&hist[pairs[i].y & 63], 1);
    __syncthreads();
    if (threadIdx.x == 0) {
        int r = 0;
        for (int t = 0; t < 64; ++t) { loff[t] = r; r += hist[t]; }
    }
    __syncthreads();
    if (threadIdx.x < 64) {
        int node = b * 64 + (int)threadIdx.x;
        if (node < N) {
            int c = hist[threadIdx.x];
            counts[node] = c;
            rowoff[node] = base + loff[threadIdx.x];
            dinv[node] = rsqrtf((float)c + 1.0f);
        }
    }
    __syncthreads();
    if (threadIdx.x < 64) hist[threadIdx.x] = loff[threadIdx.x];  // reuse as cursor
    __syncthreads();
    for (int i = base + (int)threadIdx.x; i < end; i += 256) {
        int2 p = pairs[i];
        int pos = atomicAdd(&hist[p.y & 63], 1);
        srt[base + pos] = p.x;  // contiguous ~8KB window per block
    }
}

// --- register-blocked tiled GEMM: H[N,OUT] = X[N,IN] @ W[IN,OUT] -----------
template <int IN, int OUT, int TN>
__global__ __launch_bounds__(256) void k_gemm_tile(const float* __restrict__ X,
                                                   const float* __restrict__ W,
                                                   float* __restrict__ H, int N) {
    constexpr int ROWS = 64;
    constexpr int CT = OUT / TN;    // 16 for both shapes
    constexpr int RT = 256 / CT;    // 16
    constexpr int TM = ROWS / RT;   // 4
    static_assert(CT * RT == 256 && TM * RT == ROWS, "tile mismatch");
    __shared__ float Xs[ROWS][IN];
    __shared__ float Ws[IN][OUT];

    const int tid = threadIdx.x;
    const int row0 = blockIdx.x * ROWS;

    for (int i = tid; i < IN * OUT / 4; i += 256)
        ((float4*)Ws)[i] = ((const float4*)W)[i];
    for (int i = tid; i < ROWS * IN / 4; i += 256) {
        int r = i / (IN / 4), kq = i % (IN / 4);
        float4 v = make_float4(0.f, 0.f, 0.f, 0.f);
        if (row0 + r < N) v = *(const float4*)(X + (size_t)(row0 + r) * IN + kq * 4);
        *(float4*)&Xs[r][kq * 4] = v;
    }
    __syncthreads();

    const int tx = tid % CT;
    const int ty = tid / CT;

    float acc[TM][TN];
#pragma unroll
    for (int m = 0; m < TM; ++m)
#pragma unroll
        for (int n = 0; n < TN; ++n) acc[m][n] = 0.0f;

#pragma unroll 2
    for (int kq = 0; kq < IN / 4; ++kq) {
        float a[TM][4];
#pragma unroll
        for (int m = 0; m < TM; ++m) {
            float4 t = *(const float4*)&Xs[ty * TM + m][kq * 4];
            a[m][0] = t.x; a[m][1] = t.y; a[m][2] = t.z; a[m][3] = t.w;
        }
#pragma unroll
        for (int j = 0; j < 4; ++j) {
            float b[TN];
#pragma unroll
            for (int n4 = 0; n4 < TN / 4; ++n4) {
                float4 t = *(const float4*)&Ws[kq * 4 + j][tx * TN + n4 * 4];
                b[n4 * 4 + 0] = t.x; b[n4 * 4 + 1] = t.y;
                b[n4 * 4 + 2] = t.z; b[n4 * 4 + 3] = t.w;
            }
#pragma unroll
            for (int m = 0; m < TM; ++m)
#pragma unroll
                for (int n = 0; n < TN; ++n)
                    acc[m][n] = fmaf(a[m][j], b[n], acc[m][n]);
        }
    }

#pragma unroll
    for (int m = 0; m < TM; ++m) {
        int r = row0 + ty * TM + m;
        if (r >= N) continue;
#pragma unroll
        for (int n4 = 0; n4 < TN / 4; ++n4) {
            float4 o = make_float4(acc[m][n4 * 4 + 0], acc[m][n4 * 4 + 1],
                                   acc[m][n4 * 4 + 2], acc[m][n4 * 4 + 3]);
            *(float4*)(H + (size_t)r * OUT + tx * TN + n4 * 4) = o;
        }
    }
}

// --- fused aggregation: O[d] = relu(bias + sum_{e: dst=d} H[src]*w + H[d]*dinv^2)
__global__ void k_agg_csr64(const int* __restrict__ srt, const int* __restrict__ rowoff,
                            const int* __restrict__ counts, const float* __restrict__ dinv,
                            const float* __restrict__ H, const float* __restrict__ bias,
                            float* __restrict__ O, int N) {
    int node = blockIdx.x * (blockDim.x >> 6) + (threadIdx.x >> 6);
    int lane = threadIdx.x & 63;
    if (node >= N) return;
    float dv = dinv[node];
    float acc = H[(size_t)node * 64 + lane] * dv * dv;  // self-loop
    const int* sp = srt + rowoff[node];
    int ce = counts[node];
    int e = 0;
    for (; e + 1 < ce; e += 2) {
        int sa = sp[e], sb = sp[e + 1];
        float wa = dinv[sa] * dv;
        float wb = dinv[sb] * dv;
        float ha = H[(size_t)sa * 64 + lane];
        float hb = H[(size_t)sb * 64 + lane];
        acc = fmaf(ha, wa, acc);
        acc = fmaf(hb, wb, acc);
    }
    if (e < ce) {
        int sa = sp[e];
        acc = fmaf(H[(size_t)sa * 64 + lane], dinv[sa] * dv, acc);
    }
    O[(size_t)node * 64 + lane] = fmaxf(acc + bias[lane], 0.0f);
}

__global__ void k_agg_csr128(const int* __restrict__ srt, const int* __restrict__ rowoff,
                             const int* __restrict__ counts, const float* __restrict__ dinv,
                             const float* __restrict__ H, const float* __restrict__ bias,
                             float* __restrict__ O, int N) {
    int node = blockIdx.x * (blockDim.x >> 6) + (threadIdx.x >> 6);
    int lane = threadIdx.x & 63;
    if (node >= N) return;
    const float2* H2 = (const float2*)H;
    float dv = dinv[node];
    float2 hv = H2[(size_t)node * 64 + lane];
    float ax = hv.x * dv * dv, ay = hv.y * dv * dv;  // self-loop
    const int* sp = srt + rowoff[node];
    int ce = counts[node];
    int e = 0;
    for (; e + 1 < ce; e += 2) {
        int sa = sp[e], sb = sp[e + 1];
        float wa = dinv[sa] * dv;
        float wb = dinv[sb] * dv;
        float2 va = H2[(size_t)sa * 64 + lane];
        float2 vb = H2[(size_t)sb * 64 + lane];
        ax = fmaf(va.x, wa, ax); ay = fmaf(va.y, wa, ay);
        ax = fmaf(vb.x, wb, ax); ay = fmaf(vb.y, wb, ay);
    }
    if (e < ce) {
        int sa = sp[e];
        float wa = dinv[sa] * dv;
        float2 va = H2[(size_t)sa * 64 + lane];
        ax = fmaf(va.x, wa, ax); ay = fmaf(va.y, wa, ay);
    }
    float2 b2 = ((const float2*)bias)[lane];
    float2 o;
    o.x = fmaxf(ax + b2.x, 0.0f);
    o.y = fmaxf(ay + b2.y, 0.0f);
    ((float2*)O)[(size_t)node * 64 + lane] = o;
}

// --- pooling (batch sorted): wave-run accumulation ------------------------
__global__ void k_zero_f(float* p, int n) {
    int i = blockIdx.x * blockDim.x + threadIdx.x;
    if (i < n) p[i] = 0.0f;
}

__global__ void k_pool_seg(const float* __restrict__ H, const int* __restrict__ batch,
                           float* __restrict__ sums, float* __restrict__ cnt, int N) {
    int gw = (blockIdx.x * blockDim.x + threadIdx.x) >> 6;
    int lane = threadIdx.x & 63;
    int start = gw * 64;
    if (start >= N) return;
    int end = min(N, start + 64);
    int gcur = batch[start];
    float acc = 0.0f, c = 0.0f;
    for (int i = start; i < end; ++i) {
        int g = batch[i];
        if (g != gcur) {
            atomicAdd(&sums[(size_t)gcur * 64 + lane], acc);
            if (lane == 0) atomicAdd(&cnt[gcur], c);
            acc = 0.0f; c = 0.0f; gcur = g;
        }
        acc += H[(size_t)i * 64 + lane];
        c += 1.0f;
    }
    atomicAdd(&sums[(size_t)gcur * 64 + lane], acc);
    if (lane == 0) atomicAdd(&cnt[gcur], c);
}

// --- head: mean, fc, log_softmax ------------------------------------------
__global__ void k_head(const float* __restrict__ sums, const float* __restrict__ cnt,
                       const float* __restrict__ fcw, const float* __restrict__ fcb,
                       float* __restrict__ out, int G) {
    int g = blockIdx.x * blockDim.x + threadIdx.x;
    if (g >= G) return;
    float inv = 1.0f / fmaxf(cnt[g], 1.0f);
    float l[6];
#pragma unroll
    for (int c = 0; c < 6; ++c) {
        float acc = fcb[c];
        for (int f = 0; f < 64; ++f)
            acc = fmaf(sums[(size_t)g * 64 + f] * inv, fcw[f * 6 + c], acc);
        l[c] = acc;
    }
    float m = l[0];
#pragma unroll
    for (int c = 1; c < 6; ++c) m = fmaxf(m, l[c]);
    float se = 0.0f;
#pragma unroll
    for (int c = 0; c < 6; ++c) se += expf(l[c] - m);
    float lse = m + logf(se);
#pragma unroll
    for (int c = 0; c < 6; ++c) out[(size_t)g * 6 + c] = l[c] - lse;
}

// ---------------------------------------------------------------------------
extern "C" void kernel_launch(void* const* d_in, const int* in_sizes, int n_in,
                              void* d_out, int out_size, void* d_ws, size_t ws_size,
                              hipStream_t stream) {
    const float* x    = (const float*)d_in[0];
    const int*   eidx = (const int*)d_in[1];
    const int*   batch= (const int*)d_in[2];
    const float* W1   = (const float*)d_in[3];
    const float* b1   = (const float*)d_in[4];
    const float* W2   = (const float*)d_in[5];
    const float* b2   = (const float*)d_in[6];
    const float* W3   = (const float*)d_in[7];
    const float* b3   = (const float*)d_in[8];
    const float* fcw  = (const float*)d_in[9];
    const float* fcb  = (const float*)d_in[10];
    float* out = (float*)d_out;

    const int N = in_sizes[2];          // 100000
    const int E = in_sizes[1] / 2;      // 3200000
    const int G = out_size / 6;         // 512
    const int NBUK = (N + 63) / 64;     // 1563

    const int* src = eidx;
    const int* dst = eidx + E;

    float* ws = (float*)d_ws;
    size_t off = 0;
    auto take = [&](size_t n4) {
        float* p = ws + off;
        off += (n4 + 15) & ~(size_t)15;
        return p;
    };
    float* dinv   = take((size_t)N);
    int*   srt    = (int*)take((size_t)E);
    int*   rowoff = (int*)take((size_t)N);
    int*   counts = (int*)take((size_t)N);
    int*   bcnt   = (int*)take((size_t)NBUK + 1);
    int*   bbase  = (int*)take((size_t)NBUK + 1);
    int*   bcur   = (int*)take((size_t)NBUK + 1);
    float* bufA   = take((size_t)N * 128);
    float* bufB   = take((size_t)N * 128);
    float* sums   = take((size_t)G * 64);
    float* cnt    = take((size_t)G);
    (void)ws_size;

    int2* pairs = (int2*)bufA;  // alias: dead before first GEMM writes bufA

    const int B = 256;

    // --- binned CSR build ---
    k_zero_int<<<grid_for(NBUK, B), B, 0, stream>>>(bcnt, NBUK);
    k_bucket_count<<<grid_for(E, B), B, 0, stream>>>(dst, bcnt, E);
    k_bucket_scan<<<1, 256, 0, stream>>>(bcnt, bbase, bcur, NBUK, E);
    k_bin<<<grid_for(E, B), B, 0, stream>>>(src, dst, bcur, pairs, E);
    k_bucket_csr<<<NBUK, 256, 0, stream>>>(pairs, bbase, srt, counts, rowoff, dinv, N);

    // --- layer 1: x[N,128] -> h[N,64] -> agg+relu -> bufB[N,64] ---
    k_gemm_tile<128, 64, 4><<<grid_for(N, 64), B, 0, stream>>>(x, W1, bufA, N);
    k_agg_csr64<<<grid_for(N, 4), B, 0, stream>>>(srt, rowoff, counts, dinv, bufA, b1, bufB, N);

    // --- layer 2: bufB[N,64] -> h[N,128] -> agg+relu -> bufB[N,128] ---
    k_gemm_tile<64, 128, 8><<<grid_for(N, 64), B, 0, stream>>>(bufB, W2, bufA, N);
    k_agg_csr128<<<grid_for(N, 4), B, 0, stream>>>(srt, rowoff, counts, dinv, bufA, b2, bufB, N);

    // --- layer 3: bufB[N,128] -> h[N,64] -> agg+relu -> bufB[N,64] ---
    k_gemm_tile<128, 64, 4><<<grid_for(N, 64), B, 0, stream>>>(bufB, W3, bufA, N);
    k_agg_csr64<<<grid_for(N, 4), B, 0, stream>>>(srt, rowoff, counts, dinv, bufA, b3, bufB, N);

    // --- pool + head ---
    k_zero_f<<<grid_for(G * 64, B), B, 0, stream>>>(sums, G * 64);
    k_zero_f<<<grid_for(G, B), B, 0, stream>>>(cnt, G);
    k_pool_seg<<<grid_for((long long)grid_for(N, 64) * 64, B), B, 0, stream>>>(bufB, batch, sums, cnt, N);
    k_head<<<grid_for(G, 64), 64, 0, stream>>>(sums, cnt, fcw, fcb, out, G);
}

// Round 5
// 1077.989 us; speedup vs baseline: 1.5858x; 1.5858x over previous
//
#include <hip/hip_runtime.h>

// ---------------------------------------------------------------------------
// GCN forward: 3x GCNConv(+relu) -> global_mean_pool -> fc -> log_softmax
// N=100000 nodes, E=3200000 edges, G=512 graphs, feats 128->64->128->64
// R4: revert R3 binning (regressed). CSR build = counting sort with
// XCD-class-partitioned count/scatter: class j = dst&7, grid (chunks x 8),
// block (c,j) handles only class-j edges -> each srt/cursor line has a single
// writer XCD (round-robin dispatch heuristic; correctness mapping-independent).
// Cursor/count accumulators in class-major layout [(d&7)<<14 | d>>3].
// ---------------------------------------------------------------------------

static inline int grid_for(long long total, int block) {
    return (int)((total + block - 1) / block);
}

#define CLS_SHIFT 14  // per-class capacity 16384 >= ceil(N/8)

// --- CSR build -------------------------------------------------------------
__global__ void k_zero_int(int* p, int n) {
    int i = blockIdx.x * blockDim.x + threadIdx.x;
    if (i < n) p[i] = 0;
}

// class-partitioned degree count: ccls[(d&7)<<14 | d>>3] += 1
__global__ void k_count_cls(const int* __restrict__ dst, int* __restrict__ ccls,
                            int E, int nchunk) {
    const int j = blockIdx.y;
    const int V4 = E >> 2;
    const int per = (V4 + nchunk - 1) / nchunk;
    const int lo = blockIdx.x * per;
    const int hi = min(V4, lo + per);
    for (int i4 = lo + (int)threadIdx.x; i4 < hi; i4 += blockDim.x) {
        int4 d4 = ((const int4*)dst)[i4];
        if ((d4.x & 7) == j) atomicAdd(&ccls[(j << CLS_SHIFT) + (d4.x >> 3)], 1);
        if ((d4.y & 7) == j) atomicAdd(&ccls[(j << CLS_SHIFT) + (d4.y >> 3)], 1);
        if ((d4.z & 7) == j) atomicAdd(&ccls[(j << CLS_SHIFT) + (d4.z >> 3)], 1);
        if ((d4.w & 7) == j) atomicAdd(&ccls[(j << CLS_SHIFT) + (d4.w >> 3)], 1);
    }
    if (blockIdx.x == 0 && threadIdx.x == 0) {  // scalar tail (E%4)
        for (int i = V4 << 2; i < E; ++i) {
            int d = dst[i];
            if ((d & 7) == j) atomicAdd(&ccls[(j << CLS_SHIFT) + (d >> 3)], 1);
        }
    }
}

// per-block inclusive scan over node-ordered counts (gathered from class layout)
__global__ void k_scan_block(const int* __restrict__ ccls, int* __restrict__ rowoff,
                             int* __restrict__ partials, int N) {
    __shared__ int s[256];
    int tid = threadIdx.x;
    int i = blockIdx.x * 256 + tid;
    int v = (i < N) ? ccls[((i & 7) << CLS_SHIFT) + (i >> 3)] : 0;
    s[tid] = v;
    __syncthreads();
    for (int off = 1; off < 256; off <<= 1) {
        int t = (tid >= off) ? s[tid - off] : 0;
        __syncthreads();
        s[tid] += t;
        __syncthreads();
    }
    if (i < N) rowoff[i] = s[tid];
    if (tid == 255) partials[blockIdx.x] = s[255];
}

__global__ void k_scan_partials(int* __restrict__ partials, int nblk) {
    __shared__ int s[512];
    int tid = threadIdx.x;
    int v = (tid < nblk) ? partials[tid] : 0;
    s[tid] = v;
    __syncthreads();
    for (int off = 1; off < 512; off <<= 1) {
        int t = (tid >= off) ? s[tid - off] : 0;
        __syncthreads();
        s[tid] += t;
        __syncthreads();
    }
    if (tid < nblk) partials[tid] = s[tid] - v;  // exclusive
}

// rowoff := exclusive scan (node order); cursor (class layout) := rowoff;
// counts (node order); dinv := rsqrt(deg+1)
__global__ void k_finalize(const int* __restrict__ ccls, int* __restrict__ rowoff,
                           const int* __restrict__ partials, int* __restrict__ curcls,
                           int* __restrict__ counts, float* __restrict__ dinv, int N) {
    int i = blockIdx.x * blockDim.x + threadIdx.x;
    if (i >= N) return;
    int v = ccls[((i & 7) << CLS_SHIFT) + (i >> 3)];
    int excl = rowoff[i] - v + partials[i >> 8];
    rowoff[i] = excl;
    curcls[((i & 7) << CLS_SHIFT) + (i >> 3)] = excl;
    counts[i] = v;
    dinv[i] = rsqrtf((float)v + 1.0f);
}

// class-partitioned scatter: block (c,j) places only edges with (dst&7)==j
__global__ void k_scatter_cls(const int* __restrict__ src, const int* __restrict__ dst,
                              int* __restrict__ curcls, int* __restrict__ srt,
                              int E, int nchunk) {
    const int j = blockIdx.y;
    const int V4 = E >> 2;
    const int per = (V4 + nchunk - 1) / nchunk;
    const int lo = blockIdx.x * per;
    const int hi = min(V4, lo + per);
    for (int i4 = lo + (int)threadIdx.x; i4 < hi; i4 += blockDim.x) {
        int4 d4 = ((const int4*)dst)[i4];
        int4 s4 = ((const int4*)src)[i4];
        if ((d4.x & 7) == j) srt[atomicAdd(&curcls[(j << CLS_SHIFT) + (d4.x >> 3)], 1)] = s4.x;
        if ((d4.y & 7) == j) srt[atomicAdd(&curcls[(j << CLS_SHIFT) + (d4.y >> 3)], 1)] = s4.y;
        if ((d4.z & 7) == j) srt[atomicAdd(&curcls[(j << CLS_SHIFT) + (d4.z >> 3)], 1)] = s4.z;
        if ((d4.w & 7) == j) srt[atomicAdd(&curcls[(j << CLS_SHIFT) + (d4.w >> 3)], 1)] = s4.w;
    }
    if (blockIdx.x == 0 && threadIdx.x == 0) {  // scalar tail
        for (int i = V4 << 2; i < E; ++i) {
            int d = dst[i];
            if ((d & 7) == j)
                srt[atomicAdd(&curcls[(j << CLS_SHIFT) + (d >> 3)], 1)] = src[i];
        }
    }
}

// --- register-blocked tiled GEMM: H[N,OUT] = X[N,IN] @ W[IN,OUT] -----------
template <int IN, int OUT, int TN>
__global__ __launch_bounds__(256) void k_gemm_tile(const float* __restrict__ X,
                                                   const float* __restrict__ W,
                                                   float* __restrict__ H, int N) {
    constexpr int ROWS = 64;
    constexpr int CT = OUT / TN;
    constexpr int RT = 256 / CT;
    constexpr int TM = ROWS / RT;
    static_assert(CT * RT == 256 && TM * RT == ROWS, "tile mismatch");
    __shared__ float Xs[ROWS][IN];
    __shared__ float Ws[IN][OUT];

    const int tid = threadIdx.x;
    const int row0 = blockIdx.x * ROWS;

    for (int i = tid; i < IN * OUT / 4; i += 256)
        ((float4*)Ws)[i] = ((const float4*)W)[i];
    for (int i = tid; i < ROWS * IN / 4; i += 256) {
        int r = i / (IN / 4), kq = i % (IN / 4);
        float4 v = make_float4(0.f, 0.f, 0.f, 0.f);
        if (row0 + r < N) v = *(const float4*)(X + (size_t)(row0 + r) * IN + kq * 4);
        *(float4*)&Xs[r][kq * 4] = v;
    }
    __syncthreads();

    const int tx = tid % CT;
    const int ty = tid / CT;

    float acc[TM][TN];
#pragma unroll
    for (int m = 0; m < TM; ++m)
#pragma unroll
        for (int n = 0; n < TN; ++n) acc[m][n] = 0.0f;

#pragma unroll 2
    for (int kq = 0; kq < IN / 4; ++kq) {
        float a[TM][4];
#pragma unroll
        for (int m = 0; m < TM; ++m) {
            float4 t = *(const float4*)&Xs[ty * TM + m][kq * 4];
            a[m][0] = t.x; a[m][1] = t.y; a[m][2] = t.z; a[m][3] = t.w;
        }
#pragma unroll
        for (int j = 0; j < 4; ++j) {
            float b[TN];
#pragma unroll
            for (int n4 = 0; n4 < TN / 4; ++n4) {
                float4 t = *(const float4*)&Ws[kq * 4 + j][tx * TN + n4 * 4];
                b[n4 * 4 + 0] = t.x; b[n4 * 4 + 1] = t.y;
                b[n4 * 4 + 2] = t.z; b[n4 * 4 + 3] = t.w;
            }
#pragma unroll
            for (int m = 0; m < TM; ++m)
#pragma unroll
                for (int n = 0; n < TN; ++n)
                    acc[m][n] = fmaf(a[m][j], b[n], acc[m][n]);
        }
    }

#pragma unroll
    for (int m = 0; m < TM; ++m) {
        int r = row0 + ty * TM + m;
        if (r >= N) continue;
#pragma unroll
        for (int n4 = 0; n4 < TN / 4; ++n4) {
            float4 o = make_float4(acc[m][n4 * 4 + 0], acc[m][n4 * 4 + 1],
                                   acc[m][n4 * 4 + 2], acc[m][n4 * 4 + 3]);
            *(float4*)(H + (size_t)r * OUT + tx * TN + n4 * 4) = o;
        }
    }
}

// --- fused aggregation: O[d] = relu(bias + sum_{e: dst=d} H[src]*w + H[d]*dinv^2)
__global__ void k_agg_csr64(const int* __restrict__ srt, const int* __restrict__ rowoff,
                            const int* __restrict__ counts, const float* __restrict__ dinv,
                            const float* __restrict__ H, const float* __restrict__ bias,
                            float* __restrict__ O, int N) {
    int node = blockIdx.x * (blockDim.x >> 6) + (threadIdx.x >> 6);
    int lane = threadIdx.x & 63;
    if (node >= N) return;
    float dv = dinv[node];
    float acc = H[(size_t)node * 64 + lane] * dv * dv;  // self-loop
    const int* sp = srt + rowoff[node];
    int ce = counts[node];
    int e = 0;
    for (; e + 1 < ce; e += 2) {
        int sa = sp[e], sb = sp[e + 1];
        float wa = dinv[sa] * dv;
        float wb = dinv[sb] * dv;
        float ha = H[(size_t)sa * 64 + lane];
        float hb = H[(size_t)sb * 64 + lane];
        acc = fmaf(ha, wa, acc);
        acc = fmaf(hb, wb, acc);
    }
    if (e < ce) {
        int sa = sp[e];
        acc = fmaf(H[(size_t)sa * 64 + lane], dinv[sa] * dv, acc);
    }
    O[(size_t)node * 64 + lane] = fmaxf(acc + bias[lane], 0.0f);
}

__global__ void k_agg_csr128(const int* __restrict__ srt, const int* __restrict__ rowoff,
                             const int* __restrict__ counts, const float* __restrict__ dinv,
                             const float* __restrict__ H, const float* __restrict__ bias,
                             float* __restrict__ O, int N) {
    int node = blockIdx.x * (blockDim.x >> 6) + (threadIdx.x >> 6);
    int lane = threadIdx.x & 63;
    if (node >= N) return;
    const float2* H2 = (const float2*)H;
    float dv = dinv[node];
    float2 hv = H2[(size_t)node * 64 + lane];
    float ax = hv.x * dv * dv, ay = hv.y * dv * dv;  // self-loop
    const int* sp = srt + rowoff[node];
    int ce = counts[node];
    int e = 0;
    for (; e + 1 < ce; e += 2) {
        int sa = sp[e], sb = sp[e + 1];
        float wa = dinv[sa] * dv;
        float wb = dinv[sb] * dv;
        float2 va = H2[(size_t)sa * 64 + lane];
        float2 vb = H2[(size_t)sb * 64 + lane];
        ax = fmaf(va.x, wa, ax); ay = fmaf(va.y, wa, ay);
        ax = fmaf(vb.x, wb, ax); ay = fmaf(vb.y, wb, ay);
    }
    if (e < ce) {
        int sa = sp[e];
        float wa = dinv[sa] * dv;
        float2 va = H2[(size_t)sa * 64 + lane];
        ax = fmaf(va.x, wa, ax); ay = fmaf(va.y, wa, ay);
    }
    float2 b2 = ((const float2*)bias)[lane];
    float2 o;
    o.x = fmaxf(ax + b2.x, 0.0f);
    o.y = fmaxf(ay + b2.y, 0.0f);
    ((float2*)O)[(size_t)node * 64 + lane] = o;
}

// --- pooling (batch sorted): wave-run accumulation ------------------------
__global__ void k_zero_f(float* p, int n) {
    int i = blockIdx.x * blockDim.x + threadIdx.x;
    if (i < n) p[i] = 0.0f;
}

__global__ void k_pool_seg(const float* __restrict__ H, const int* __restrict__ batch,
                           float* __restrict__ sums, float* __restrict__ cnt, int N) {
    int gw = (blockIdx.x * blockDim.x + threadIdx.x) >> 6;
    int lane = threadIdx.x & 63;
    int start = gw * 64;
    if (start >= N) return;
    int end = min(N, start + 64);
    int gcur = batch[start];
    float acc = 0.0f, c = 0.0f;
    for (int i = start; i < end; ++i) {
        int g = batch[i];
        if (g != gcur) {
            atomicAdd(&sums[(size_t)gcur * 64 + lane], acc);
            if (lane == 0) atomicAdd(&cnt[gcur], c);
            acc = 0.0f; c = 0.0f; gcur = g;
        }
        acc += H[(size_t)i * 64 + lane];
        c += 1.0f;
    }
    atomicAdd(&sums[(size_t)gcur * 64 + lane], acc);
    if (lane == 0) atomicAdd(&cnt[gcur], c);
}

// --- head: mean, fc, log_softmax ------------------------------------------
__global__ void k_head(const float* __restrict__ sums, const float* __restrict__ cnt,
                       const float* __restrict__ fcw, const float* __restrict__ fcb,
                       float* __restrict__ out, int G) {
    int g = blockIdx.x * blockDim.x + threadIdx.x;
    if (g >= G) return;
    float inv = 1.0f / fmaxf(cnt[g], 1.0f);
    float l[6];
#pragma unroll
    for (int c = 0; c < 6; ++c) {
        float acc = fcb[c];
        for (int f = 0; f < 64; ++f)
            acc = fmaf(sums[(size_t)g * 64 + f] * inv, fcw[f * 6 + c], acc);
        l[c] = acc;
    }
    float m = l[0];
#pragma unroll
    for (int c = 1; c < 6; ++c) m = fmaxf(m, l[c]);
    float se = 0.0f;
#pragma unroll
    for (int c = 0; c < 6; ++c) se += expf(l[c] - m);
    float lse = m + logf(se);
#pragma unroll
    for (int c = 0; c < 6; ++c) out[(size_t)g * 6 + c] = l[c] - lse;
}

// ---------------------------------------------------------------------------
extern "C" void kernel_launch(void* const* d_in, const int* in_sizes, int n_in,
                              void* d_out, int out_size, void* d_ws, size_t ws_size,
                              hipStream_t stream) {
    const float* x    = (const float*)d_in[0];
    const int*   eidx = (const int*)d_in[1];
    const int*   batch= (const int*)d_in[2];
    const float* W1   = (const float*)d_in[3];
    const float* b1   = (const float*)d_in[4];
    const float* W2   = (const float*)d_in[5];
    const float* b2   = (const float*)d_in[6];
    const float* W3   = (const float*)d_in[7];
    const float* b3   = (const float*)d_in[8];
    const float* fcw  = (const float*)d_in[9];
    const float* fcb  = (const float*)d_in[10];
    float* out = (float*)d_out;

    const int N = in_sizes[2];          // 100000
    const int E = in_sizes[1] / 2;      // 3200000
    const int G = out_size / 6;         // 512
    const int CLSTOT = 8 << CLS_SHIFT;  // 8 classes x 16384

    const int* src = eidx;
    const int* dst = eidx + E;

    float* ws = (float*)d_ws;
    size_t off = 0;
    auto take = [&](size_t n4) {
        float* p = ws + off;
        off += (n4 + 15) & ~(size_t)15;
        return p;
    };
    float* dinv    = take((size_t)N);
    int*   srt     = (int*)take((size_t)E);
    int*   rowoff  = (int*)take((size_t)N);
    int*   counts  = (int*)take((size_t)N);
    int*   ccls    = (int*)take((size_t)CLSTOT);
    int*   curcls  = (int*)take((size_t)CLSTOT);
    int*   partials= (int*)take(512);
    float* bufA    = take((size_t)N * 128);
    float* bufB    = take((size_t)N * 128);
    float* sums    = take((size_t)G * 64);
    float* cnt     = take((size_t)G);
    (void)ws_size;

    const int B = 256;
    const int NBLK = grid_for(N, 256);
    const int NCHUNK = 512;
    dim3 clsgrid(NCHUNK, 8);

    // --- CSR build (class-partitioned counting sort) ---
    k_zero_int<<<grid_for(CLSTOT, B), B, 0, stream>>>(ccls, CLSTOT);
    k_count_cls<<<clsgrid, B, 0, stream>>>(dst, ccls, E, NCHUNK);
    k_scan_block<<<NBLK, 256, 0, stream>>>(ccls, rowoff, partials, N);
    k_scan_partials<<<1, 512, 0, stream>>>(partials, NBLK);
    k_finalize<<<grid_for(N, B), B, 0, stream>>>(ccls, rowoff, partials, curcls, counts, dinv, N);
    k_scatter_cls<<<clsgrid, B, 0, stream>>>(src, dst, curcls, srt, E, NCHUNK);

    // --- layer 1: x[N,128] -> h[N,64] -> agg+relu -> bufB[N,64] ---
    k_gemm_tile<128, 64, 4><<<grid_for(N, 64), B, 0, stream>>>(x, W1, bufA, N);
    k_agg_csr64<<<grid_for(N, 4), B, 0, stream>>>(srt, rowoff, counts, dinv, bufA, b1, bufB, N);

    // --- layer 2: bufB[N,64] -> h[N,128] -> agg+relu -> bufB[N,128] ---
    k_gemm_tile<64, 128, 8><<<grid_for(N, 64), B, 0, stream>>>(bufB, W2, bufA, N);
    k_agg_csr128<<<grid_for(N, 4), B, 0, stream>>>(srt, rowoff, counts, dinv, bufA, b2, bufB, N);

    // --- layer 3: bufB[N,128] -> h[N,64] -> agg+relu -> bufB[N,64] ---
    k_gemm_tile<128, 64, 4><<<grid_for(N, 64), B, 0, stream>>>(bufB, W3, bufA, N);
    k_agg_csr64<<<grid_for(N, 4), B, 0, stream>>>(srt, rowoff, counts, dinv, bufA, b3, bufB, N);

    // --- pool + head ---
    k_zero_f<<<grid_for(G * 64, B), B, 0, stream>>>(sums, G * 64);
    k_zero_f<<<grid_for(G, B), B, 0, stream>>>(cnt, G);
    k_pool_seg<<<grid_for((long long)grid_for(N, 64) * 64, B), B, 0, stream>>>(bufB, batch, sums, cnt, N);
    k_head<<<grid_for(G, 64), 64, 0, stream>>>(sums, cnt, fcw, fcb, out, G);
}

// Round 6
// 860.429 us; speedup vs baseline: 1.9868x; 1.2528x over previous
//
#include <hip/hip_runtime.h>

// ---------------------------------------------------------------------------
// GCN forward: 3x GCNConv(+relu) -> global_mean_pool -> fc -> log_softmax
// N=100000 nodes, E=3200000 edges, G=512 graphs, feats 128->64->128->64
// R5: layer 2 restructured as (A_norm @ X) @ W2  (aggregate-first) so ALL
// aggregations run at F=64 (halves layer-2 gather bytes). Bias+ReLU for
// layer 2 fused into the GEMM epilogue. Agg edge-loop unrolled x4 for MLP.
// CSR build: R4's XCD-class-partitioned counting sort (single-writer lines).
// ---------------------------------------------------------------------------

static inline int grid_for(long long total, int block) {
    return (int)((total + block - 1) / block);
}

#define CLS_SHIFT 14  // per-class capacity 16384 >= ceil(N/8)

// --- CSR build -------------------------------------------------------------
__global__ void k_zero_int(int* p, int n) {
    int i = blockIdx.x * blockDim.x + threadIdx.x;
    if (i < n) p[i] = 0;
}

__global__ void k_count_cls(const int* __restrict__ dst, int* __restrict__ ccls,
                            int E, int nchunk) {
    const int j = blockIdx.y;
    const int V4 = E >> 2;
    const int per = (V4 + nchunk - 1) / nchunk;
    const int lo = blockIdx.x * per;
    const int hi = min(V4, lo + per);
    for (int i4 = lo + (int)threadIdx.x; i4 < hi; i4 += blockDim.x) {
        int4 d4 = ((const int4*)dst)[i4];
        if ((d4.x & 7) == j) atomicAdd(&ccls[(j << CLS_SHIFT) + (d4.x >> 3)], 1);
        if ((d4.y & 7) == j) atomicAdd(&ccls[(j << CLS_SHIFT) + (d4.y >> 3)], 1);
        if ((d4.z & 7) == j) atomicAdd(&ccls[(j << CLS_SHIFT) + (d4.z >> 3)], 1);
        if ((d4.w & 7) == j) atomicAdd(&ccls[(j << CLS_SHIFT) + (d4.w >> 3)], 1);
    }
    if (blockIdx.x == 0 && threadIdx.x == 0) {
        for (int i = V4 << 2; i < E; ++i) {
            int d = dst[i];
            if ((d & 7) == j) atomicAdd(&ccls[(j << CLS_SHIFT) + (d >> 3)], 1);
        }
    }
}

__global__ void k_scan_block(const int* __restrict__ ccls, int* __restrict__ rowoff,
                             int* __restrict__ partials, int N) {
    __shared__ int s[256];
    int tid = threadIdx.x;
    int i = blockIdx.x * 256 + tid;
    int v = (i < N) ? ccls[((i & 7) << CLS_SHIFT) + (i >> 3)] : 0;
    s[tid] = v;
    __syncthreads();
    for (int off = 1; off < 256; off <<= 1) {
        int t = (tid >= off) ? s[tid - off] : 0;
        __syncthreads();
        s[tid] += t;
        __syncthreads();
    }
    if (i < N) rowoff[i] = s[tid];
    if (tid == 255) partials[blockIdx.x] = s[255];
}

__global__ void k_scan_partials(int* __restrict__ partials, int nblk) {
    __shared__ int s[512];
    int tid = threadIdx.x;
    int v = (tid < nblk) ? partials[tid] : 0;
    s[tid] = v;
    __syncthreads();
    for (int off = 1; off < 512; off <<= 1) {
        int t = (tid >= off) ? s[tid - off] : 0;
        __syncthreads();
        s[tid] += t;
        __syncthreads();
    }
    if (tid < nblk) partials[tid] = s[tid] - v;  // exclusive
}

__global__ void k_finalize(const int* __restrict__ ccls, int* __restrict__ rowoff,
                           const int* __restrict__ partials, int* __restrict__ curcls,
                           int* __restrict__ counts, float* __restrict__ dinv, int N) {
    int i = blockIdx.x * blockDim.x + threadIdx.x;
    if (i >= N) return;
    int v = ccls[((i & 7) << CLS_SHIFT) + (i >> 3)];
    int excl = rowoff[i] - v + partials[i >> 8];
    rowoff[i] = excl;
    curcls[((i & 7) << CLS_SHIFT) + (i >> 3)] = excl;
    counts[i] = v;
    dinv[i] = rsqrtf((float)v + 1.0f);
}

__global__ void k_scatter_cls(const int* __restrict__ src, const int* __restrict__ dst,
                              int* __restrict__ curcls, int* __restrict__ srt,
                              int E, int nchunk) {
    const int j = blockIdx.y;
    const int V4 = E >> 2;
    const int per = (V4 + nchunk - 1) / nchunk;
    const int lo = blockIdx.x * per;
    const int hi = min(V4, lo + per);
    for (int i4 = lo + (int)threadIdx.x; i4 < hi; i4 += blockDim.x) {
        int4 d4 = ((const int4*)dst)[i4];
        int4 s4 = ((const int4*)src)[i4];
        if ((d4.x & 7) == j) srt[atomicAdd(&curcls[(j << CLS_SHIFT) + (d4.x >> 3)], 1)] = s4.x;
        if ((d4.y & 7) == j) srt[atomicAdd(&curcls[(j << CLS_SHIFT) + (d4.y >> 3)], 1)] = s4.y;
        if ((d4.z & 7) == j) srt[atomicAdd(&curcls[(j << CLS_SHIFT) + (d4.z >> 3)], 1)] = s4.z;
        if ((d4.w & 7) == j) srt[atomicAdd(&curcls[(j << CLS_SHIFT) + (d4.w >> 3)], 1)] = s4.w;
    }
    if (blockIdx.x == 0 && threadIdx.x == 0) {
        for (int i = V4 << 2; i < E; ++i) {
            int d = dst[i];
            if ((d & 7) == j)
                srt[atomicAdd(&curcls[(j << CLS_SHIFT) + (d >> 3)], 1)] = src[i];
        }
    }
}

// --- register-blocked tiled GEMM: H[N,OUT] = X[N,IN] @ W[IN,OUT] -----------
// BR: fuse out = relu(out + bias) in the epilogue.
template <int IN, int OUT, int TN, bool BR>
__global__ __launch_bounds__(256) void k_gemm_tile(const float* __restrict__ X,
                                                   const float* __restrict__ W,
                                                   const float* __restrict__ bias,
                                                   float* __restrict__ H, int N) {
    constexpr int ROWS = 64;
    constexpr int CT = OUT / TN;
    constexpr int RT = 256 / CT;
    constexpr int TM = ROWS / RT;
    static_assert(CT * RT == 256 && TM * RT == ROWS, "tile mismatch");
    __shared__ float Xs[ROWS][IN];
    __shared__ float Ws[IN][OUT];

    const int tid = threadIdx.x;
    const int row0 = blockIdx.x * ROWS;

    for (int i = tid; i < IN * OUT / 4; i += 256)
        ((float4*)Ws)[i] = ((const float4*)W)[i];
    for (int i = tid; i < ROWS * IN / 4; i += 256) {
        int r = i / (IN / 4), kq = i % (IN / 4);
        float4 v = make_float4(0.f, 0.f, 0.f, 0.f);
        if (row0 + r < N) v = *(const float4*)(X + (size_t)(row0 + r) * IN + kq * 4);
        *(float4*)&Xs[r][kq * 4] = v;
    }
    __syncthreads();

    const int tx = tid % CT;
    const int ty = tid / CT;

    float acc[TM][TN];
#pragma unroll
    for (int m = 0; m < TM; ++m)
#pragma unroll
        for (int n = 0; n < TN; ++n) acc[m][n] = 0.0f;

#pragma unroll 2
    for (int kq = 0; kq < IN / 4; ++kq) {
        float a[TM][4];
#pragma unroll
        for (int m = 0; m < TM; ++m) {
            float4 t = *(const float4*)&Xs[ty * TM + m][kq * 4];
            a[m][0] = t.x; a[m][1] = t.y; a[m][2] = t.z; a[m][3] = t.w;
        }
#pragma unroll
        for (int j = 0; j < 4; ++j) {
            float b[TN];
#pragma unroll
            for (int n4 = 0; n4 < TN / 4; ++n4) {
                float4 t = *(const float4*)&Ws[kq * 4 + j][tx * TN + n4 * 4];
                b[n4 * 4 + 0] = t.x; b[n4 * 4 + 1] = t.y;
                b[n4 * 4 + 2] = t.z; b[n4 * 4 + 3] = t.w;
            }
#pragma unroll
            for (int m = 0; m < TM; ++m)
#pragma unroll
                for (int n = 0; n < TN; ++n)
                    acc[m][n] = fmaf(a[m][j], b[n], acc[m][n]);
        }
    }

#pragma unroll
    for (int m = 0; m < TM; ++m) {
        int r = row0 + ty * TM + m;
        if (r >= N) continue;
#pragma unroll
        for (int n4 = 0; n4 < TN / 4; ++n4) {
            float4 o = make_float4(acc[m][n4 * 4 + 0], acc[m][n4 * 4 + 1],
                                   acc[m][n4 * 4 + 2], acc[m][n4 * 4 + 3]);
            if (BR) {
                float4 b4 = *(const float4*)&bias[tx * TN + n4 * 4];
                o.x = fmaxf(o.x + b4.x, 0.0f);
                o.y = fmaxf(o.y + b4.y, 0.0f);
                o.z = fmaxf(o.z + b4.z, 0.0f);
                o.w = fmaxf(o.w + b4.w, 0.0f);
            }
            *(float4*)(H + (size_t)r * OUT + tx * TN + n4 * 4) = o;
        }
    }
}

// --- F=64 aggregation, unrolled x4 for MLP.
// BR: O = relu(agg + bias); else O = agg (pure A_norm apply).
template <bool BR>
__global__ void k_agg_csr64(const int* __restrict__ srt, const int* __restrict__ rowoff,
                            const int* __restrict__ counts, const float* __restrict__ dinv,
                            const float* __restrict__ H, const float* __restrict__ bias,
                            float* __restrict__ O, int N) {
    int node = blockIdx.x * (blockDim.x >> 6) + (threadIdx.x >> 6);
    int lane = threadIdx.x & 63;
    if (node >= N) return;
    float dv = dinv[node];
    float acc = H[(size_t)node * 64 + lane] * dv * dv;  // self-loop
    const int* sp = srt + rowoff[node];
    int ce = counts[node];
    int e = 0;
    for (; e + 3 < ce; e += 4) {
        int s0 = sp[e], s1 = sp[e + 1], s2 = sp[e + 2], s3 = sp[e + 3];
        float w0 = dinv[s0] * dv, w1 = dinv[s1] * dv;
        float w2 = dinv[s2] * dv, w3 = dinv[s3] * dv;
        float h0 = H[(size_t)s0 * 64 + lane];
        float h1 = H[(size_t)s1 * 64 + lane];
        float h2 = H[(size_t)s2 * 64 + lane];
        float h3 = H[(size_t)s3 * 64 + lane];
        acc = fmaf(h0, w0, acc);
        acc = fmaf(h1, w1, acc);
        acc = fmaf(h2, w2, acc);
        acc = fmaf(h3, w3, acc);
    }
    for (; e < ce; ++e) {
        int s0 = sp[e];
        acc = fmaf(H[(size_t)s0 * 64 + lane], dinv[s0] * dv, acc);
    }
    if (BR) acc = fmaxf(acc + bias[lane], 0.0f);
    O[(size_t)node * 64 + lane] = acc;
}

// --- pooling (batch sorted): wave-run accumulation ------------------------
__global__ void k_zero_f(float* p, int n) {
    int i = blockIdx.x * blockDim.x + threadIdx.x;
    if (i < n) p[i] = 0.0f;
}

__global__ void k_pool_seg(const float* __restrict__ H, const int* __restrict__ batch,
                           float* __restrict__ sums, float* __restrict__ cnt, int N) {
    int gw = (blockIdx.x * blockDim.x + threadIdx.x) >> 6;
    int lane = threadIdx.x & 63;
    int start = gw * 64;
    if (start >= N) return;
    int end = min(N, start + 64);
    int gcur = batch[start];
    float acc = 0.0f, c = 0.0f;
    for (int i = start; i < end; ++i) {
        int g = batch[i];
        if (g != gcur) {
            atomicAdd(&sums[(size_t)gcur * 64 + lane], acc);
            if (lane == 0) atomicAdd(&cnt[gcur], c);
            acc = 0.0f; c = 0.0f; gcur = g;
        }
        acc += H[(size_t)i * 64 + lane];
        c += 1.0f;
    }
    atomicAdd(&sums[(size_t)gcur * 64 + lane], acc);
    if (lane == 0) atomicAdd(&cnt[gcur], c);
}

// --- head: mean, fc, log_softmax ------------------------------------------
__global__ void k_head(const float* __restrict__ sums, const float* __restrict__ cnt,
                       const float* __restrict__ fcw, const float* __restrict__ fcb,
                       float* __restrict__ out, int G) {
    int g = blockIdx.x * blockDim.x + threadIdx.x;
    if (g >= G) return;
    float inv = 1.0f / fmaxf(cnt[g], 1.0f);
    float l[6];
#pragma unroll
    for (int c = 0; c < 6; ++c) {
        float acc = fcb[c];
        for (int f = 0; f < 64; ++f)
            acc = fmaf(sums[(size_t)g * 64 + f] * inv, fcw[f * 6 + c], acc);
        l[c] = acc;
    }
    float m = l[0];
#pragma unroll
    for (int c = 1; c < 6; ++c) m = fmaxf(m, l[c]);
    float se = 0.0f;
#pragma unroll
    for (int c = 0; c < 6; ++c) se += expf(l[c] - m);
    float lse = m + logf(se);
#pragma unroll
    for (int c = 0; c < 6; ++c) out[(size_t)g * 6 + c] = l[c] - lse;
}

// ---------------------------------------------------------------------------
extern "C" void kernel_launch(void* const* d_in, const int* in_sizes, int n_in,
                              void* d_out, int out_size, void* d_ws, size_t ws_size,
                              hipStream_t stream) {
    const float* x    = (const float*)d_in[0];
    const int*   eidx = (const int*)d_in[1];
    const int*   batch= (const int*)d_in[2];
    const float* W1   = (const float*)d_in[3];
    const float* b1   = (const float*)d_in[4];
    const float* W2   = (const float*)d_in[5];
    const float* b2   = (const float*)d_in[6];
    const float* W3   = (const float*)d_in[7];
    const float* b3   = (const float*)d_in[8];
    const float* fcw  = (const float*)d_in[9];
    const float* fcb  = (const float*)d_in[10];
    float* out = (float*)d_out;

    const int N = in_sizes[2];          // 100000
    const int E = in_sizes[1] / 2;      // 3200000
    const int G = out_size / 6;         // 512
    const int CLSTOT = 8 << CLS_SHIFT;  // 8 classes x 16384

    const int* src = eidx;
    const int* dst = eidx + E;

    float* ws = (float*)d_ws;
    size_t off = 0;
    auto take = [&](size_t n4) {
        float* p = ws + off;
        off += (n4 + 15) & ~(size_t)15;
        return p;
    };
    float* dinv    = take((size_t)N);
    int*   srt     = (int*)take((size_t)E);
    int*   rowoff  = (int*)take((size_t)N);
    int*   counts  = (int*)take((size_t)N);
    int*   ccls    = (int*)take((size_t)CLSTOT);
    int*   curcls  = (int*)take((size_t)CLSTOT);
    int*   partials= (int*)take(512);
    float* bufA    = take((size_t)N * 128);
    float* bufB    = take((size_t)N * 128);
    float* sums    = take((size_t)G * 64);
    float* cnt     = take((size_t)G);
    (void)ws_size;

    const int B = 256;
    const int NBLK = grid_for(N, 256);
    const int NCHUNK = 512;
    dim3 clsgrid(NCHUNK, 8);

    // --- CSR build (class-partitioned counting sort) ---
    k_zero_int<<<grid_for(CLSTOT, B), B, 0, stream>>>(ccls, CLSTOT);
    k_count_cls<<<clsgrid, B, 0, stream>>>(dst, ccls, E, NCHUNK);
    k_scan_block<<<NBLK, 256, 0, stream>>>(ccls, rowoff, partials, N);
    k_scan_partials<<<1, 512, 0, stream>>>(partials, NBLK);
    k_finalize<<<grid_for(N, B), B, 0, stream>>>(ccls, rowoff, partials, curcls, counts, dinv, N);
    k_scatter_cls<<<clsgrid, B, 0, stream>>>(src, dst, curcls, srt, E, NCHUNK);

    // --- layer 1: h = x@W1 (transform-first), agg+bias+relu -> bufB[N,64] ---
    k_gemm_tile<128, 64, 4, false><<<grid_for(N, 64), B, 0, stream>>>(x, W1, nullptr, bufA, N);
    k_agg_csr64<true><<<grid_for(N, 4), B, 0, stream>>>(srt, rowoff, counts, dinv, bufA, b1, bufB, N);

    // --- layer 2 (aggregate-first): a = A_norm@bufB [N,64], then
    //     bufB = relu(a@W2 + b2) [N,128] ---
    k_agg_csr64<false><<<grid_for(N, 4), B, 0, stream>>>(srt, rowoff, counts, dinv, bufB, nullptr, bufA, N);
    k_gemm_tile<64, 128, 8, true><<<grid_for(N, 64), B, 0, stream>>>(bufA, W2, b2, bufB, N);

    // --- layer 3: h = bufB@W3 (transform-first), agg+bias+relu -> bufB[N,64] ---
    k_gemm_tile<128, 64, 4, false><<<grid_for(N, 64), B, 0, stream>>>(bufB, W3, nullptr, bufA, N);
    k_agg_csr64<true><<<grid_for(N, 4), B, 0, stream>>>(srt, rowoff, counts, dinv, bufA, b3, bufB, N);

    // --- pool + head ---
    k_zero_f<<<grid_for(G * 64, B), B, 0, stream>>>(sums, G * 64);
    k_zero_f<<<grid_for(G, B), B, 0, stream>>>(cnt, G);
    k_pool_seg<<<grid_for((long long)grid_for(N, 64) * 64, B), B, 0, stream>>>(bufB, batch, sums, cnt, N);
    k_head<<<grid_for(G, 64), 64, 0, stream>>>(sums, cnt, fcw, fcb, out, G);
}

// Round 7
// 848.230 us; speedup vs baseline: 2.0154x; 1.0144x over previous
//
#include <hip/hip_runtime.h>

// ---------------------------------------------------------------------------
// GCN forward: 3x GCNConv(+relu) -> global_mean_pool -> fc -> log_softmax
// N=100000 nodes, E=3200000 edges, G=512 graphs, feats 128->64->128->64
// R6: fix XCD class-partition grid orientation. Blocks dispatch x-fastest and
// round-robin across 8 XCDs by linear id, so class MUST be blockIdx.x:
// linear = chunk*8 + class -> XCD = class. (R4/R5 had it transposed; every
// class spanned all XCDs and write amplification stayed ~16x.)
// Layer 2 aggregate-first (all aggs F=64); agg unrolled x4; CSR gather.
// ---------------------------------------------------------------------------

static inline int grid_for(long long total, int block) {
    return (int)((total + block - 1) / block);
}

#define CLS_SHIFT 14  // per-class capacity 16384 >= ceil(N/8)

// --- CSR build -------------------------------------------------------------
__global__ void k_zero_int(int* p, int n) {
    int i = blockIdx.x * blockDim.x + threadIdx.x;
    if (i < n) p[i] = 0;
}

// class j = blockIdx.x  (XCD-pinned under round-robin linear dispatch)
__global__ void k_count_cls(const int* __restrict__ dst, int* __restrict__ ccls,
                            int E, int nchunk) {
    const int j = blockIdx.x;
    const int V4 = E >> 2;
    const int per = (V4 + nchunk - 1) / nchunk;
    const int lo = blockIdx.y * per;
    const int hi = min(V4, lo + per);
    for (int i4 = lo + (int)threadIdx.x; i4 < hi; i4 += blockDim.x) {
        int4 d4 = ((const int4*)dst)[i4];
        if ((d4.x & 7) == j) atomicAdd(&ccls[(j << CLS_SHIFT) + (d4.x >> 3)], 1);
        if ((d4.y & 7) == j) atomicAdd(&ccls[(j << CLS_SHIFT) + (d4.y >> 3)], 1);
        if ((d4.z & 7) == j) atomicAdd(&ccls[(j << CLS_SHIFT) + (d4.z >> 3)], 1);
        if ((d4.w & 7) == j) atomicAdd(&ccls[(j << CLS_SHIFT) + (d4.w >> 3)], 1);
    }
    if (blockIdx.y == 0 && threadIdx.x == 0) {  // scalar tail (E%4)
        for (int i = V4 << 2; i < E; ++i) {
            int d = dst[i];
            if ((d & 7) == j) atomicAdd(&ccls[(j << CLS_SHIFT) + (d >> 3)], 1);
        }
    }
}

__global__ void k_scan_block(const int* __restrict__ ccls, int* __restrict__ rowoff,
                             int* __restrict__ partials, int N) {
    __shared__ int s[256];
    int tid = threadIdx.x;
    int i = blockIdx.x * 256 + tid;
    int v = (i < N) ? ccls[((i & 7) << CLS_SHIFT) + (i >> 3)] : 0;
    s[tid] = v;
    __syncthreads();
    for (int off = 1; off < 256; off <<= 1) {
        int t = (tid >= off) ? s[tid - off] : 0;
        __syncthreads();
        s[tid] += t;
        __syncthreads();
    }
    if (i < N) rowoff[i] = s[tid];
    if (tid == 255) partials[blockIdx.x] = s[255];
}

__global__ void k_scan_partials(int* __restrict__ partials, int nblk) {
    __shared__ int s[512];
    int tid = threadIdx.x;
    int v = (tid < nblk) ? partials[tid] : 0;
    s[tid] = v;
    __syncthreads();
    for (int off = 1; off < 512; off <<= 1) {
        int t = (tid >= off) ? s[tid - off] : 0;
        __syncthreads();
        s[tid] += t;
        __syncthreads();
    }
    if (tid < nblk) partials[tid] = s[tid] - v;  // exclusive
}

__global__ void k_finalize(const int* __restrict__ ccls, int* __restrict__ rowoff,
                           const int* __restrict__ partials, int* __restrict__ curcls,
                           int* __restrict__ counts, float* __restrict__ dinv, int N) {
    int i = blockIdx.x * blockDim.x + threadIdx.x;
    if (i >= N) return;
    int v = ccls[((i & 7) << CLS_SHIFT) + (i >> 3)];
    int excl = rowoff[i] - v + partials[i >> 8];
    rowoff[i] = excl;
    curcls[((i & 7) << CLS_SHIFT) + (i >> 3)] = excl;
    counts[i] = v;
    dinv[i] = rsqrtf((float)v + 1.0f);
}

__global__ void k_scatter_cls(const int* __restrict__ src, const int* __restrict__ dst,
                              int* __restrict__ curcls, int* __restrict__ srt,
                              int E, int nchunk) {
    const int j = blockIdx.x;
    const int V4 = E >> 2;
    const int per = (V4 + nchunk - 1) / nchunk;
    const int lo = blockIdx.y * per;
    const int hi = min(V4, lo + per);
    for (int i4 = lo + (int)threadIdx.x; i4 < hi; i4 += blockDim.x) {
        int4 d4 = ((const int4*)dst)[i4];
        int4 s4 = ((const int4*)src)[i4];
        if ((d4.x & 7) == j) srt[atomicAdd(&curcls[(j << CLS_SHIFT) + (d4.x >> 3)], 1)] = s4.x;
        if ((d4.y & 7) == j) srt[atomicAdd(&curcls[(j << CLS_SHIFT) + (d4.y >> 3)], 1)] = s4.y;
        if ((d4.z & 7) == j) srt[atomicAdd(&curcls[(j << CLS_SHIFT) + (d4.z >> 3)], 1)] = s4.z;
        if ((d4.w & 7) == j) srt[atomicAdd(&curcls[(j << CLS_SHIFT) + (d4.w >> 3)], 1)] = s4.w;
    }
    if (blockIdx.y == 0 && threadIdx.x == 0) {  // scalar tail
        for (int i = V4 << 2; i < E; ++i) {
            int d = dst[i];
            if ((d & 7) == j)
                srt[atomicAdd(&curcls[(j << CLS_SHIFT) + (d >> 3)], 1)] = src[i];
        }
    }
}

// --- register-blocked tiled GEMM: H[N,OUT] = X[N,IN] @ W[IN,OUT] -----------
// BR: fuse out = relu(out + bias) in the epilogue.
template <int IN, int OUT, int TN, bool BR>
__global__ __launch_bounds__(256) void k_gemm_tile(const float* __restrict__ X,
                                                   const float* __restrict__ W,
                                                   const float* __restrict__ bias,
                                                   float* __restrict__ H, int N) {
    constexpr int ROWS = 64;
    constexpr int CT = OUT / TN;
    constexpr int RT = 256 / CT;
    constexpr int TM = ROWS / RT;
    static_assert(CT * RT == 256 && TM * RT == ROWS, "tile mismatch");
    __shared__ float Xs[ROWS][IN];
    __shared__ float Ws[IN][OUT];

    const int tid = threadIdx.x;
    const int row0 = blockIdx.x * ROWS;

    for (int i = tid; i < IN * OUT / 4; i += 256)
        ((float4*)Ws)[i] = ((const float4*)W)[i];
    for (int i = tid; i < ROWS * IN / 4; i += 256) {
        int r = i / (IN / 4), kq = i % (IN / 4);
        float4 v = make_float4(0.f, 0.f, 0.f, 0.f);
        if (row0 + r < N) v = *(const float4*)(X + (size_t)(row0 + r) * IN + kq * 4);
        *(float4*)&Xs[r][kq * 4] = v;
    }
    __syncthreads();

    const int tx = tid % CT;
    const int ty = tid / CT;

    float acc[TM][TN];
#pragma unroll
    for (int m = 0; m < TM; ++m)
#pragma unroll
        for (int n = 0; n < TN; ++n) acc[m][n] = 0.0f;

#pragma unroll 2
    for (int kq = 0; kq < IN / 4; ++kq) {
        float a[TM][4];
#pragma unroll
        for (int m = 0; m < TM; ++m) {
            float4 t = *(const float4*)&Xs[ty * TM + m][kq * 4];
            a[m][0] = t.x; a[m][1] = t.y; a[m][2] = t.z; a[m][3] = t.w;
        }
#pragma unroll
        for (int j = 0; j < 4; ++j) {
            float b[TN];
#pragma unroll
            for (int n4 = 0; n4 < TN / 4; ++n4) {
                float4 t = *(const float4*)&Ws[kq * 4 + j][tx * TN + n4 * 4];
                b[n4 * 4 + 0] = t.x; b[n4 * 4 + 1] = t.y;
                b[n4 * 4 + 2] = t.z; b[n4 * 4 + 3] = t.w;
            }
#pragma unroll
            for (int m = 0; m < TM; ++m)
#pragma unroll
                for (int n = 0; n < TN; ++n)
                    acc[m][n] = fmaf(a[m][j], b[n], acc[m][n]);
        }
    }

#pragma unroll
    for (int m = 0; m < TM; ++m) {
        int r = row0 + ty * TM + m;
        if (r >= N) continue;
#pragma unroll
        for (int n4 = 0; n4 < TN / 4; ++n4) {
            float4 o = make_float4(acc[m][n4 * 4 + 0], acc[m][n4 * 4 + 1],
                                   acc[m][n4 * 4 + 2], acc[m][n4 * 4 + 3]);
            if (BR) {
                float4 b4 = *(const float4*)&bias[tx * TN + n4 * 4];
                o.x = fmaxf(o.x + b4.x, 0.0f);
                o.y = fmaxf(o.y + b4.y, 0.0f);
                o.z = fmaxf(o.z + b4.z, 0.0f);
                o.w = fmaxf(o.w + b4.w, 0.0f);
            }
            *(float4*)(H + (size_t)r * OUT + tx * TN + n4 * 4) = o;
        }
    }
}

// --- F=64 aggregation, unrolled x4 for MLP.
// BR: O = relu(agg + bias); else O = agg (pure A_norm apply).
template <bool BR>
__global__ void k_agg_csr64(const int* __restrict__ srt, const int* __restrict__ rowoff,
                            const int* __restrict__ counts, const float* __restrict__ dinv,
                            const float* __restrict__ H, const float* __restrict__ bias,
                            float* __restrict__ O, int N) {
    int node = blockIdx.x * (blockDim.x >> 6) + (threadIdx.x >> 6);
    int lane = threadIdx.x & 63;
    if (node >= N) return;
    float dv = dinv[node];
    float acc = H[(size_t)node * 64 + lane] * dv * dv;  // self-loop
    const int* sp = srt + rowoff[node];
    int ce = counts[node];
    int e = 0;
    for (; e + 3 < ce; e += 4) {
        int s0 = sp[e], s1 = sp[e + 1], s2 = sp[e + 2], s3 = sp[e + 3];
        float w0 = dinv[s0] * dv, w1 = dinv[s1] * dv;
        float w2 = dinv[s2] * dv, w3 = dinv[s3] * dv;
        float h0 = H[(size_t)s0 * 64 + lane];
        float h1 = H[(size_t)s1 * 64 + lane];
        float h2 = H[(size_t)s2 * 64 + lane];
        float h3 = H[(size_t)s3 * 64 + lane];
        acc = fmaf(h0, w0, acc);
        acc = fmaf(h1, w1, acc);
        acc = fmaf(h2, w2, acc);
        acc = fmaf(h3, w3, acc);
    }
    for (; e < ce; ++e) {
        int s0 = sp[e];
        acc = fmaf(H[(size_t)s0 * 64 + lane], dinv[s0] * dv, acc);
    }
    if (BR) acc = fmaxf(acc + bias[lane], 0.0f);
    O[(size_t)node * 64 + lane] = acc;
}

// --- pooling (batch sorted): wave-run accumulation ------------------------
__global__ void k_zero_f(float* p, int n) {
    int i = blockIdx.x * blockDim.x + threadIdx.x;
    if (i < n) p[i] = 0.0f;
}

__global__ void k_pool_seg(const float* __restrict__ H, const int* __restrict__ batch,
                           float* __restrict__ sums, float* __restrict__ cnt, int N) {
    int gw = (blockIdx.x * blockDim.x + threadIdx.x) >> 6;
    int lane = threadIdx.x & 63;
    int start = gw * 64;
    if (start >= N) return;
    int end = min(N, start + 64);
    int gcur = batch[start];
    float acc = 0.0f, c = 0.0f;
    for (int i = start; i < end; ++i) {
        int g = batch[i];
        if (g != gcur) {
            atomicAdd(&sums[(size_t)gcur * 64 + lane], acc);
            if (lane == 0) atomicAdd(&cnt[gcur], c);
            acc = 0.0f; c = 0.0f; gcur = g;
        }
        acc += H[(size_t)i * 64 + lane];
        c += 1.0f;
    }
    atomicAdd(&sums[(size_t)gcur * 64 + lane], acc);
    if (lane == 0) atomicAdd(&cnt[gcur], c);
}

// --- head: mean, fc, log_softmax ------------------------------------------
__global__ void k_head(const float* __restrict__ sums, const float* __restrict__ cnt,
                       const float* __restrict__ fcw, const float* __restrict__ fcb,
                       float* __restrict__ out, int G) {
    int g = blockIdx.x * blockDim.x + threadIdx.x;
    if (g >= G) return;
    float inv = 1.0f / fmaxf(cnt[g], 1.0f);
    float l[6];
#pragma unroll
    for (int c = 0; c < 6; ++c) {
        float acc = fcb[c];
        for (int f = 0; f < 64; ++f)
            acc = fmaf(sums[(size_t)g * 64 + f] * inv, fcw[f * 6 + c], acc);
        l[c] = acc;
    }
    float m = l[0];
#pragma unroll
    for (int c = 1; c < 6; ++c) m = fmaxf(m, l[c]);
    float se = 0.0f;
#pragma unroll
    for (int c = 0; c < 6; ++c) se += expf(l[c] - m);
    float lse = m + logf(se);
#pragma unroll
    for (int c = 0; c < 6; ++c) out[(size_t)g * 6 + c] = l[c] - lse;
}

// ---------------------------------------------------------------------------
extern "C" void kernel_launch(void* const* d_in, const int* in_sizes, int n_in,
                              void* d_out, int out_size, void* d_ws, size_t ws_size,
                              hipStream_t stream) {
    const float* x    = (const float*)d_in[0];
    const int*   eidx = (const int*)d_in[1];
    const int*   batch= (const int*)d_in[2];
    const float* W1   = (const float*)d_in[3];
    const float* b1   = (const float*)d_in[4];
    const float* W2   = (const float*)d_in[5];
    const float* b2   = (const float*)d_in[6];
    const float* W3   = (const float*)d_in[7];
    const float* b3   = (const float*)d_in[8];
    const float* fcw  = (const float*)d_in[9];
    const float* fcb  = (const float*)d_in[10];
    float* out = (float*)d_out;

    const int N = in_sizes[2];          // 100000
    const int E = in_sizes[1] / 2;      // 3200000
    const int G = out_size / 6;         // 512
    const int CLSTOT = 8 << CLS_SHIFT;  // 8 classes x 16384

    const int* src = eidx;
    const int* dst = eidx + E;

    float* ws = (float*)d_ws;
    size_t off = 0;
    auto take = [&](size_t n4) {
        float* p = ws + off;
        off += (n4 + 15) & ~(size_t)15;
        return p;
    };
    float* dinv    = take((size_t)N);
    int*   srt     = (int*)take((size_t)E);
    int*   rowoff  = (int*)take((size_t)N);
    int*   counts  = (int*)take((size_t)N);
    int*   ccls    = (int*)take((size_t)CLSTOT);
    int*   curcls  = (int*)take((size_t)CLSTOT);
    int*   partials= (int*)take(512);
    float* bufA    = take((size_t)N * 128);
    float* bufB    = take((size_t)N * 128);
    float* sums    = take((size_t)G * 64);
    float* cnt     = take((size_t)G);
    (void)ws_size;

    const int B = 256;
    const int NBLK = grid_for(N, 256);
    const int NCHUNK = 512;
    dim3 clsgrid(8, NCHUNK);  // class = blockIdx.x -> XCD = linear%8 = class

    // --- CSR build (class-partitioned counting sort) ---
    k_zero_int<<<grid_for(CLSTOT, B), B, 0, stream>>>(ccls, CLSTOT);
    k_count_cls<<<clsgrid, B, 0, stream>>>(dst, ccls, E, NCHUNK);
    k_scan_block<<<NBLK, 256, 0, stream>>>(ccls, rowoff, partials, N);
    k_scan_partials<<<1, 512, 0, stream>>>(partials, NBLK);
    k_finalize<<<grid_for(N, B), B, 0, stream>>>(ccls, rowoff, partials, curcls, counts, dinv, N);
    k_scatter_cls<<<clsgrid, B, 0, stream>>>(src, dst, curcls, srt, E, NCHUNK);

    // --- layer 1: h = x@W1 (transform-first), agg+bias+relu -> bufB[N,64] ---
    k_gemm_tile<128, 64, 4, false><<<grid_for(N, 64), B, 0, stream>>>(x, W1, nullptr, bufA, N);
    k_agg_csr64<true><<<grid_for(N, 4), B, 0, stream>>>(srt, rowoff, counts, dinv, bufA, b1, bufB, N);

    // --- layer 2 (aggregate-first): a = A_norm@bufB [N,64], then
    //     bufB = relu(a@W2 + b2) [N,128] ---
    k_agg_csr64<false><<<grid_for(N, 4), B, 0, stream>>>(srt, rowoff, counts, dinv, bufB, nullptr, bufA, N);
    k_gemm_tile<64, 128, 8, true><<<grid_for(N, 64), B, 0, stream>>>(bufA, W2, b2, bufB, N);

    // --- layer 3: h = bufB@W3 (transform-first), agg+bias+relu -> bufB[N,64] ---
    k_gemm_tile<128, 64, 4, false><<<grid_for(N, 64), B, 0, stream>>>(bufB, W3, nullptr, bufA, N);
    k_agg_csr64<true><<<grid_for(N, 4), B, 0, stream>>>(srt, rowoff, counts, dinv, bufA, b3, bufB, N);

    // --- pool + head ---
    k_zero_f<<<grid_for(G * 64, B), B, 0, stream>>>(sums, G * 64);
    k_zero_f<<<grid_for(G, B), B, 0, stream>>>(cnt, G);
    k_pool_seg<<<grid_for((long long)grid_for(N, 64) * 64, B), B, 0, stream>>>(bufB, batch, sums, cnt, N);
    k_head<<<grid_for(G, 64), 64, 0, stream>>>(sums, cnt, fcw, fcb, out, G);
}

// Round 8
// 593.507 us; speedup vs baseline: 2.8804x; 1.4292x over previous
//
#include <hip/hip_runtime.h>

// ---------------------------------------------------------------------------
// GCN forward: 3x GCNConv(+relu) -> global_mean_pool -> fc -> log_softmax
// N=100000 nodes, E=3200000 edges, G=512 graphs, feats 128->64->128->64
// R7: CSR build rebuilt as LDS-binned two-level radix:
//   histA (LDS hist, no global atomics) -> linear scan -> binB (per-block
//   LDS cursors, sequential writes per (bucket,block) region, ~1x write amp)
//   -> bucketC (per-bucket in-LDS counting sort; emits srt+counts+rowoff+dinv).
// Layer 2 aggregate-first (all aggs F=64); agg unrolled x4; CSR gather.
// ---------------------------------------------------------------------------

static inline int grid_for(long long total, int block) {
    return (int)((total + block - 1) / block);
}

#define NB_BIN 512    // binning blocks
#define BUK_SHIFT 9   // 512 nodes per bucket; nbuk = ceil(N/512) (<=256)

// --- pass A: per-(block,bucket) LDS histogram, transposed out --------------
__global__ __launch_bounds__(256) void k_histA(const int* __restrict__ dst,
                                               int* __restrict__ histT,
                                               int E, int nbuk) {
    __shared__ int h[256];
    const int c = blockIdx.x;
    for (int i = threadIdx.x; i < nbuk; i += 256) h[i] = 0;
    __syncthreads();
    const int per = (E + NB_BIN - 1) / NB_BIN;
    const int lo = c * per, hi = min(E, lo + per);
    for (int i = lo + (int)threadIdx.x; i < hi; i += 256)
        atomicAdd(&h[dst[i] >> BUK_SHIFT], 1);
    __syncthreads();
    for (int i = threadIdx.x; i < nbuk; i += 256)
        histT[i * NB_BIN + c] = h[i];
}

// --- linear 2-level scan ---------------------------------------------------
__global__ void k_scan_block_lin(const int* __restrict__ in, int* __restrict__ outI,
                                 int* __restrict__ partials, int M) {
    __shared__ int s[256];
    int tid = threadIdx.x;
    int i = blockIdx.x * 256 + tid;
    int v = (i < M) ? in[i] : 0;
    s[tid] = v;
    __syncthreads();
    for (int off = 1; off < 256; off <<= 1) {
        int t = (tid >= off) ? s[tid - off] : 0;
        __syncthreads();
        s[tid] += t;
        __syncthreads();
    }
    if (i < M) outI[i] = s[tid];  // block-inclusive
    if (tid == 255) partials[blockIdx.x] = s[255];
}

__global__ void k_scan_partials(int* __restrict__ partials, int nblk) {
    __shared__ int s[512];
    int tid = threadIdx.x;
    int v = (tid < nblk) ? partials[tid] : 0;
    s[tid] = v;
    __syncthreads();
    for (int off = 1; off < 512; off <<= 1) {
        int t = (tid >= off) ? s[tid - off] : 0;
        __syncthreads();
        s[tid] += t;
        __syncthreads();
    }
    if (tid < nblk) partials[tid] = s[tid] - v;  // exclusive
}

// exclusive prefix at idx:  scanI[idx] - histT[idx] + partials[idx>>8]

// --- pass B: bin (src,dst) pairs; per-block LDS cursors --------------------
__global__ __launch_bounds__(256) void k_binB(const int* __restrict__ src,
                                              const int* __restrict__ dst,
                                              const int* __restrict__ histT,
                                              const int* __restrict__ scanI,
                                              const int* __restrict__ partials,
                                              int2* __restrict__ pairs,
                                              int E, int nbuk) {
    __shared__ int cur[256];
    const int c = blockIdx.x;
    for (int b = threadIdx.x; b < nbuk; b += 256) {
        int idx = b * NB_BIN + c;
        cur[b] = scanI[idx] - histT[idx] + partials[idx >> 8];
    }
    __syncthreads();
    const int per = (E + NB_BIN - 1) / NB_BIN;
    const int lo = c * per, hi = min(E, lo + per);
    for (int i = lo + (int)threadIdx.x; i < hi; i += 256) {
        int d = dst[i];
        int pos = atomicAdd(&cur[d >> BUK_SHIFT], 1);
        pairs[pos] = make_int2(src[i], d);
    }
}

// --- pass C: per-bucket counting sort + CSR metadata -----------------------
__global__ __launch_bounds__(256) void k_bucketC(const int2* __restrict__ pairs,
                                                 const int* __restrict__ histT,
                                                 const int* __restrict__ scanI,
                                                 const int* __restrict__ partials,
                                                 int* __restrict__ srt,
                                                 int* __restrict__ counts,
                                                 int* __restrict__ rowoff,
                                                 float* __restrict__ dinv,
                                                 int E, int nbuk, int N) {
    const int b = blockIdx.x;
    const int tid = threadIdx.x;
    __shared__ int h[512];
    __shared__ int loff[512];
    __shared__ int s2[256];

    // bucket [base, end) in pairs
    int idx0 = b * NB_BIN;
    int base = scanI[idx0] - histT[idx0] + partials[idx0 >> 8];
    int end;
    if (b + 1 < nbuk) {
        int idx1 = (b + 1) * NB_BIN;
        end = scanI[idx1] - histT[idx1] + partials[idx1 >> 8];
    } else {
        end = E;
    }

    const int n0 = b << BUK_SHIFT;
    const int nn = min(512, N - n0);

    h[tid] = 0; h[tid + 256] = 0;
    __syncthreads();
    for (int i = base + tid; i < end; i += 256)
        atomicAdd(&h[pairs[i].y & 511], 1);
    __syncthreads();

    // exclusive scan of h[0..512) -> loff  (pairwise + Hillis-Steele on 256)
    int a0 = h[2 * tid], a1 = h[2 * tid + 1];
    s2[tid] = a0 + a1;
    __syncthreads();
    for (int off = 1; off < 256; off <<= 1) {
        int t = (tid >= off) ? s2[tid - off] : 0;
        __syncthreads();
        s2[tid] += t;
        __syncthreads();
    }
    int e2 = s2[tid] - (a0 + a1);  // exclusive over pairs
    loff[2 * tid] = e2;
    loff[2 * tid + 1] = e2 + a0;
    __syncthreads();

    // metadata
    for (int i = tid; i < nn; i += 256) {
        int cc = h[i];
        counts[n0 + i] = cc;
        rowoff[n0 + i] = base + loff[i];
        dinv[n0 + i] = rsqrtf((float)cc + 1.0f);
    }
    __syncthreads();
    // reuse h as cursors
    h[tid] = loff[tid]; h[tid + 256] = loff[tid + 256];
    __syncthreads();
    for (int i = base + tid; i < end; i += 256) {
        int2 p = pairs[i];
        int pos = atomicAdd(&h[p.y & 511], 1);
        srt[base + pos] = p.x;
    }
}

// --- register-blocked tiled GEMM: H[N,OUT] = X[N,IN] @ W[IN,OUT] -----------
// BR: fuse out = relu(out + bias) in the epilogue.
template <int IN, int OUT, int TN, bool BR>
__global__ __launch_bounds__(256) void k_gemm_tile(const float* __restrict__ X,
                                                   const float* __restrict__ W,
                                                   const float* __restrict__ bias,
                                                   float* __restrict__ H, int N) {
    constexpr int ROWS = 64;
    constexpr int CT = OUT / TN;
    constexpr int RT = 256 / CT;
    constexpr int TM = ROWS / RT;
    static_assert(CT * RT == 256 && TM * RT == ROWS, "tile mismatch");
    __shared__ float Xs[ROWS][IN];
    __shared__ float Ws[IN][OUT];

    const int tid = threadIdx.x;
    const int row0 = blockIdx.x * ROWS;

    for (int i = tid; i < IN * OUT / 4; i += 256)
        ((float4*)Ws)[i] = ((const float4*)W)[i];
    for (int i = tid; i < ROWS * IN / 4; i += 256) {
        int r = i / (IN / 4), kq = i % (IN / 4);
        float4 v = make_float4(0.f, 0.f, 0.f, 0.f);
        if (row0 + r < N) v = *(const float4*)(X + (size_t)(row0 + r) * IN + kq * 4);
        *(float4*)&Xs[r][kq * 4] = v;
    }
    __syncthreads();

    const int tx = tid % CT;
    const int ty = tid / CT;

    float acc[TM][TN];
#pragma unroll
    for (int m = 0; m < TM; ++m)
#pragma unroll
        for (int n = 0; n < TN; ++n) acc[m][n] = 0.0f;

#pragma unroll 2
    for (int kq = 0; kq < IN / 4; ++kq) {
        float a[TM][4];
#pragma unroll
        for (int m = 0; m < TM; ++m) {
            float4 t = *(const float4*)&Xs[ty * TM + m][kq * 4];
            a[m][0] = t.x; a[m][1] = t.y; a[m][2] = t.z; a[m][3] = t.w;
        }
#pragma unroll
        for (int j = 0; j < 4; ++j) {
            float b[TN];
#pragma unroll
            for (int n4 = 0; n4 < TN / 4; ++n4) {
                float4 t = *(const float4*)&Ws[kq * 4 + j][tx * TN + n4 * 4];
                b[n4 * 4 + 0] = t.x; b[n4 * 4 + 1] = t.y;
                b[n4 * 4 + 2] = t.z; b[n4 * 4 + 3] = t.w;
            }
#pragma unroll
            for (int m = 0; m < TM; ++m)
#pragma unroll
                for (int n = 0; n < TN; ++n)
                    acc[m][n] = fmaf(a[m][j], b[n], acc[m][n]);
        }
    }

#pragma unroll
    for (int m = 0; m < TM; ++m) {
        int r = row0 + ty * TM + m;
        if (r >= N) continue;
#pragma unroll
        for (int n4 = 0; n4 < TN / 4; ++n4) {
            float4 o = make_float4(acc[m][n4 * 4 + 0], acc[m][n4 * 4 + 1],
                                   acc[m][n4 * 4 + 2], acc[m][n4 * 4 + 3]);
            if (BR) {
                float4 b4 = *(const float4*)&bias[tx * TN + n4 * 4];
                o.x = fmaxf(o.x + b4.x, 0.0f);
                o.y = fmaxf(o.y + b4.y, 0.0f);
                o.z = fmaxf(o.z + b4.z, 0.0f);
                o.w = fmaxf(o.w + b4.w, 0.0f);
            }
            *(float4*)(H + (size_t)r * OUT + tx * TN + n4 * 4) = o;
        }
    }
}

// --- F=64 aggregation, unrolled x4 for MLP.
// BR: O = relu(agg + bias); else O = agg (pure A_norm apply).
template <bool BR>
__global__ void k_agg_csr64(const int* __restrict__ srt, const int* __restrict__ rowoff,
                            const int* __restrict__ counts, const float* __restrict__ dinv,
                            const float* __restrict__ H, const float* __restrict__ bias,
                            float* __restrict__ O, int N) {
    int node = blockIdx.x * (blockDim.x >> 6) + (threadIdx.x >> 6);
    int lane = threadIdx.x & 63;
    if (node >= N) return;
    float dv = dinv[node];
    float acc = H[(size_t)node * 64 + lane] * dv * dv;  // self-loop
    const int* sp = srt + rowoff[node];
    int ce = counts[node];
    int e = 0;
    for (; e + 3 < ce; e += 4) {
        int s0 = sp[e], s1 = sp[e + 1], s2 = sp[e + 2], s3 = sp[e + 3];
        float w0 = dinv[s0] * dv, w1 = dinv[s1] * dv;
        float w2 = dinv[s2] * dv, w3 = dinv[s3] * dv;
        float h0 = H[(size_t)s0 * 64 + lane];
        float h1 = H[(size_t)s1 * 64 + lane];
        float h2 = H[(size_t)s2 * 64 + lane];
        float h3 = H[(size_t)s3 * 64 + lane];
        acc = fmaf(h0, w0, acc);
        acc = fmaf(h1, w1, acc);
        acc = fmaf(h2, w2, acc);
        acc = fmaf(h3, w3, acc);
    }
    for (; e < ce; ++e) {
        int s0 = sp[e];
        acc = fmaf(H[(size_t)s0 * 64 + lane], dinv[s0] * dv, acc);
    }
    if (BR) acc = fmaxf(acc + bias[lane], 0.0f);
    O[(size_t)node * 64 + lane] = acc;
}

// --- pooling (batch sorted): wave-run accumulation ------------------------
__global__ void k_zero_f(float* p, int n) {
    int i = blockIdx.x * blockDim.x + threadIdx.x;
    if (i < n) p[i] = 0.0f;
}

__global__ void k_pool_seg(const float* __restrict__ H, const int* __restrict__ batch,
                           float* __restrict__ sums, float* __restrict__ cnt, int N) {
    int gw = (blockIdx.x * blockDim.x + threadIdx.x) >> 6;
    int lane = threadIdx.x & 63;
    int start = gw * 64;
    if (start >= N) return;
    int end = min(N, start + 64);
    int gcur = batch[start];
    float acc = 0.0f, c = 0.0f;
    for (int i = start; i < end; ++i) {
        int g = batch[i];
        if (g != gcur) {
            atomicAdd(&sums[(size_t)gcur * 64 + lane], acc);
            if (lane == 0) atomicAdd(&cnt[gcur], c);
            acc = 0.0f; c = 0.0f; gcur = g;
        }
        acc += H[(size_t)i * 64 + lane];
        c += 1.0f;
    }
    atomicAdd(&sums[(size_t)gcur * 64 + lane], acc);
    if (lane == 0) atomicAdd(&cnt[gcur], c);
}

// --- head: mean, fc, log_softmax ------------------------------------------
__global__ void k_head(const float* __restrict__ sums, const float* __restrict__ cnt,
                       const float* __restrict__ fcw, const float* __restrict__ fcb,
                       float* __restrict__ out, int G) {
    int g = blockIdx.x * blockDim.x + threadIdx.x;
    if (g >= G) return;
    float inv = 1.0f / fmaxf(cnt[g], 1.0f);
    float l[6];
#pragma unroll
    for (int c = 0; c < 6; ++c) {
        float acc = fcb[c];
        for (int f = 0; f < 64; ++f)
            acc = fmaf(sums[(size_t)g * 64 + f] * inv, fcw[f * 6 + c], acc);
        l[c] = acc;
    }
    float m = l[0];
#pragma unroll
    for (int c = 1; c < 6; ++c) m = fmaxf(m, l[c]);
    float se = 0.0f;
#pragma unroll
    for (int c = 0; c < 6; ++c) se += expf(l[c] - m);
    float lse = m + logf(se);
#pragma unroll
    for (int c = 0; c < 6; ++c) out[(size_t)g * 6 + c] = l[c] - lse;
}

// ---------------------------------------------------------------------------
extern "C" void kernel_launch(void* const* d_in, const int* in_sizes, int n_in,
                              void* d_out, int out_size, void* d_ws, size_t ws_size,
                              hipStream_t stream) {
    const float* x    = (const float*)d_in[0];
    const int*   eidx = (const int*)d_in[1];
    const int*   batch= (const int*)d_in[2];
    const float* W1   = (const float*)d_in[3];
    const float* b1   = (const float*)d_in[4];
    const float* W2   = (const float*)d_in[5];
    const float* b2   = (const float*)d_in[6];
    const float* W3   = (const float*)d_in[7];
    const float* b3   = (const float*)d_in[8];
    const float* fcw  = (const float*)d_in[9];
    const float* fcb  = (const float*)d_in[10];
    float* out = (float*)d_out;

    const int N = in_sizes[2];          // 100000
    const int E = in_sizes[1] / 2;      // 3200000
    const int G = out_size / 6;         // 512
    const int nbuk = (N + 511) >> BUK_SHIFT;  // 196
    const int M = nbuk * NB_BIN;              // 100352

    const int* src = eidx;
    const int* dst = eidx + E;

    float* ws = (float*)d_ws;
    size_t off = 0;
    auto take = [&](size_t n4) {
        float* p = ws + off;
        off += (n4 + 15) & ~(size_t)15;
        return p;
    };
    float* dinv    = take((size_t)N);
    int*   srt     = (int*)take((size_t)E);
    int*   rowoff  = (int*)take((size_t)N);
    int*   counts  = (int*)take((size_t)N);
    int*   histT   = (int*)take((size_t)M);
    int*   scanI   = (int*)take((size_t)M);
    int*   partials= (int*)take(512);
    float* bufA    = take((size_t)N * 128);
    float* bufB    = take((size_t)N * 128);
    float* sums    = take((size_t)G * 64);
    float* cnt     = take((size_t)G);
    (void)ws_size;

    int2* pairs = (int2*)bufA;  // alias: dead before first GEMM writes bufA

    const int B = 256;
    const int NBLK_M = grid_for(M, 256);  // 392

    // --- CSR build (LDS-binned two-level radix) ---
    k_histA<<<NB_BIN, B, 0, stream>>>(dst, histT, E, nbuk);
    k_scan_block_lin<<<NBLK_M, B, 0, stream>>>(histT, scanI, partials, M);
    k_scan_partials<<<1, 512, 0, stream>>>(partials, NBLK_M);
    k_binB<<<NB_BIN, B, 0, stream>>>(src, dst, histT, scanI, partials, pairs, E, nbuk);
    k_bucketC<<<nbuk, B, 0, stream>>>(pairs, histT, scanI, partials, srt, counts,
                                      rowoff, dinv, E, nbuk, N);

    // --- layer 1: h = x@W1 (transform-first), agg+bias+relu -> bufB[N,64] ---
    k_gemm_tile<128, 64, 4, false><<<grid_for(N, 64), B, 0, stream>>>(x, W1, nullptr, bufA, N);
    k_agg_csr64<true><<<grid_for(N, 4), B, 0, stream>>>(srt, rowoff, counts, dinv, bufA, b1, bufB, N);

    // --- layer 2 (aggregate-first): a = A_norm@bufB [N,64], then
    //     bufB = relu(a@W2 + b2) [N,128] ---
    k_agg_csr64<false><<<grid_for(N, 4), B, 0, stream>>>(srt, rowoff, counts, dinv, bufB, nullptr, bufA, N);
    k_gemm_tile<64, 128, 8, true><<<grid_for(N, 64), B, 0, stream>>>(bufA, W2, b2, bufB, N);

    // --- layer 3: h = bufB@W3 (transform-first), agg+bias+relu -> bufB[N,64] ---
    k_gemm_tile<128, 64, 4, false><<<grid_for(N, 64), B, 0, stream>>>(bufB, W3, nullptr, bufA, N);
    k_agg_csr64<true><<<grid_for(N, 4), B, 0, stream>>>(srt, rowoff, counts, dinv, bufA, b3, bufB, N);

    // --- pool + head ---
    k_zero_f<<<grid_for(G * 64, B), B, 0, stream>>>(sums, G * 64);
    k_zero_f<<<grid_for(G, B), B, 0, stream>>>(cnt, G);
    k_pool_seg<<<grid_for((long long)grid_for(N, 64) * 64, B), B, 0, stream>>>(bufB, batch, sums, cnt, N);
    k_head<<<grid_for(G, 64), 64, 0, stream>>>(sums, cnt, fcw, fcb, out, G);
}

// Round 9
// 543.969 us; speedup vs baseline: 3.1427x; 1.0911x over previous
//
#include <hip/hip_runtime.h>

// ---------------------------------------------------------------------------
// GCN forward: 3x GCNConv(+relu) -> global_mean_pool -> fc -> log_softmax
// N=100000 nodes, E=3200000 edges, G=512 graphs, feats 128->64->128->64
// R8: aggregation operand stored as bf16 (halves gather bytes; the agg is
// gather-traffic bound). GEMM1/GEMM3 epilogues emit bf16; agg1 emits bf16.
// All math still fp32 (bf16 only as storage format of the gathered operand).
// CSR build: R7's LDS-binned two-level radix. Layer 2 aggregate-first.
// ---------------------------------------------------------------------------

static inline int grid_for(long long total, int block) {
    return (int)((total + block - 1) / block);
}

#define NB_BIN 512    // binning blocks
#define BUK_SHIFT 9   // 512 nodes per bucket

__device__ __forceinline__ float bf2f(unsigned short u) {
    union { unsigned int ui; float f; } c; c.ui = ((unsigned int)u) << 16; return c.f;
}
__device__ __forceinline__ unsigned short f2bf(float f) {
    union { unsigned int ui; float f; } c; c.f = f;
    unsigned int u = c.ui;
    return (unsigned short)((u + 0x7FFFu + ((u >> 16) & 1u)) >> 16);  // RNE
}

// --- pass A: per-(block,bucket) LDS histogram, transposed out --------------
__global__ __launch_bounds__(256) void k_histA(const int* __restrict__ dst,
                                               int* __restrict__ histT,
                                               int E, int nbuk) {
    __shared__ int h[256];
    const int c = blockIdx.x;
    for (int i = threadIdx.x; i < nbuk; i += 256) h[i] = 0;
    __syncthreads();
    const int per = (E + NB_BIN - 1) / NB_BIN;
    const int lo = c * per, hi = min(E, lo + per);
    for (int i = lo + (int)threadIdx.x; i < hi; i += 256)
        atomicAdd(&h[dst[i] >> BUK_SHIFT], 1);
    __syncthreads();
    for (int i = threadIdx.x; i < nbuk; i += 256)
        histT[i * NB_BIN + c] = h[i];
}

// --- linear 2-level scan ---------------------------------------------------
__global__ void k_scan_block_lin(const int* __restrict__ in, int* __restrict__ outI,
                                 int* __restrict__ partials, int M) {
    __shared__ int s[256];
    int tid = threadIdx.x;
    int i = blockIdx.x * 256 + tid;
    int v = (i < M) ? in[i] : 0;
    s[tid] = v;
    __syncthreads();
    for (int off = 1; off < 256; off <<= 1) {
        int t = (tid >= off) ? s[tid - off] : 0;
        __syncthreads();
        s[tid] += t;
        __syncthreads();
    }
    if (i < M) outI[i] = s[tid];  // block-inclusive
    if (tid == 255) partials[blockIdx.x] = s[255];
}

__global__ void k_scan_partials(int* __restrict__ partials, int nblk) {
    __shared__ int s[512];
    int tid = threadIdx.x;
    int v = (tid < nblk) ? partials[tid] : 0;
    s[tid] = v;
    __syncthreads();
    for (int off = 1; off < 512; off <<= 1) {
        int t = (tid >= off) ? s[tid - off] : 0;
        __syncthreads();
        s[tid] += t;
        __syncthreads();
    }
    if (tid < nblk) partials[tid] = s[tid] - v;  // exclusive
}

// --- pass B: bin (src,dst) pairs; per-block LDS cursors --------------------
__global__ __launch_bounds__(256) void k_binB(const int* __restrict__ src,
                                              const int* __restrict__ dst,
                                              const int* __restrict__ histT,
                                              const int* __restrict__ scanI,
                                              const int* __restrict__ partials,
                                              int2* __restrict__ pairs,
                                              int E, int nbuk) {
    __shared__ int cur[256];
    const int c = blockIdx.x;
    for (int b = threadIdx.x; b < nbuk; b += 256) {
        int idx = b * NB_BIN + c;
        cur[b] = scanI[idx] - histT[idx] + partials[idx >> 8];
    }
    __syncthreads();
    const int per = (E + NB_BIN - 1) / NB_BIN;
    const int lo = c * per, hi = min(E, lo + per);
    for (int i = lo + (int)threadIdx.x; i < hi; i += 256) {
        int d = dst[i];
        int pos = atomicAdd(&cur[d >> BUK_SHIFT], 1);
        pairs[pos] = make_int2(src[i], d);
    }
}

// --- pass C: per-bucket counting sort + CSR metadata -----------------------
__global__ __launch_bounds__(256) void k_bucketC(const int2* __restrict__ pairs,
                                                 const int* __restrict__ histT,
                                                 const int* __restrict__ scanI,
                                                 const int* __restrict__ partials,
                                                 int* __restrict__ srt,
                                                 int* __restrict__ counts,
                                                 int* __restrict__ rowoff,
                                                 float* __restrict__ dinv,
                                                 int E, int nbuk, int N) {
    const int b = blockIdx.x;
    const int tid = threadIdx.x;
    __shared__ int h[512];
    __shared__ int loff[512];
    __shared__ int s2[256];

    int idx0 = b * NB_BIN;
    int base = scanI[idx0] - histT[idx0] + partials[idx0 >> 8];
    int end;
    if (b + 1 < nbuk) {
        int idx1 = (b + 1) * NB_BIN;
        end = scanI[idx1] - histT[idx1] + partials[idx1 >> 8];
    } else {
        end = E;
    }

    const int n0 = b << BUK_SHIFT;
    const int nn = min(512, N - n0);

    h[tid] = 0; h[tid + 256] = 0;
    __syncthreads();
    for (int i = base + tid; i < end; i += 256)
        atomicAdd(&h[pairs[i].y & 511], 1);
    __syncthreads();

    int a0 = h[2 * tid], a1 = h[2 * tid + 1];
    s2[tid] = a0 + a1;
    __syncthreads();
    for (int off = 1; off < 256; off <<= 1) {
        int t = (tid >= off) ? s2[tid - off] : 0;
        __syncthreads();
        s2[tid] += t;
        __syncthreads();
    }
    int e2 = s2[tid] - (a0 + a1);
    loff[2 * tid] = e2;
    loff[2 * tid + 1] = e2 + a0;
    __syncthreads();

    for (int i = tid; i < nn; i += 256) {
        int cc = h[i];
        counts[n0 + i] = cc;
        rowoff[n0 + i] = base + loff[i];
        dinv[n0 + i] = rsqrtf((float)cc + 1.0f);
    }
    __syncthreads();
    h[tid] = loff[tid]; h[tid + 256] = loff[tid + 256];
    __syncthreads();
    for (int i = base + tid; i < end; i += 256) {
        int2 p = pairs[i];
        int pos = atomicAdd(&h[p.y & 511], 1);
        srt[base + pos] = p.x;
    }
}

// --- register-blocked tiled GEMM: H[N,OUT] = X[N,IN] @ W[IN,OUT] -----------
// BR: fuse relu(out+bias). OB: output bf16 (only for OUT=64 path, TN=4).
template <int IN, int OUT, int TN, bool BR, bool OB>
__global__ __launch_bounds__(256) void k_gemm_tile(const float* __restrict__ X,
                                                   const float* __restrict__ W,
                                                   const float* __restrict__ bias,
                                                   void* __restrict__ Hv, int N) {
    constexpr int ROWS = 64;
    constexpr int CT = OUT / TN;
    constexpr int RT = 256 / CT;
    constexpr int TM = ROWS / RT;
    static_assert(CT * RT == 256 && TM * RT == ROWS, "tile mismatch");
    __shared__ float Xs[ROWS][IN];
    __shared__ float Ws[IN][OUT];

    const int tid = threadIdx.x;
    const int row0 = blockIdx.x * ROWS;

    for (int i = tid; i < IN * OUT / 4; i += 256)
        ((float4*)Ws)[i] = ((const float4*)W)[i];
    for (int i = tid; i < ROWS * IN / 4; i += 256) {
        int r = i / (IN / 4), kq = i % (IN / 4);
        float4 v = make_float4(0.f, 0.f, 0.f, 0.f);
        if (row0 + r < N) v = *(const float4*)(X + (size_t)(row0 + r) * IN + kq * 4);
        *(float4*)&Xs[r][kq * 4] = v;
    }
    __syncthreads();

    const int tx = tid % CT;
    const int ty = tid / CT;

    float acc[TM][TN];
#pragma unroll
    for (int m = 0; m < TM; ++m)
#pragma unroll
        for (int n = 0; n < TN; ++n) acc[m][n] = 0.0f;

#pragma unroll 2
    for (int kq = 0; kq < IN / 4; ++kq) {
        float a[TM][4];
#pragma unroll
        for (int m = 0; m < TM; ++m) {
            float4 t = *(const float4*)&Xs[ty * TM + m][kq * 4];
            a[m][0] = t.x; a[m][1] = t.y; a[m][2] = t.z; a[m][3] = t.w;
        }
#pragma unroll
        for (int j = 0; j < 4; ++j) {
            float b[TN];
#pragma unroll
            for (int n4 = 0; n4 < TN / 4; ++n4) {
                float4 t = *(const float4*)&Ws[kq * 4 + j][tx * TN + n4 * 4];
                b[n4 * 4 + 0] = t.x; b[n4 * 4 + 1] = t.y;
                b[n4 * 4 + 2] = t.z; b[n4 * 4 + 3] = t.w;
            }
#pragma unroll
            for (int m = 0; m < TM; ++m)
#pragma unroll
                for (int n = 0; n < TN; ++n)
                    acc[m][n] = fmaf(a[m][j], b[n], acc[m][n]);
        }
    }

#pragma unroll
    for (int m = 0; m < TM; ++m) {
        int r = row0 + ty * TM + m;
        if (r >= N) continue;
#pragma unroll
        for (int n4 = 0; n4 < TN / 4; ++n4) {
            float4 o = make_float4(acc[m][n4 * 4 + 0], acc[m][n4 * 4 + 1],
                                   acc[m][n4 * 4 + 2], acc[m][n4 * 4 + 3]);
            if (BR) {
                float4 b4 = *(const float4*)&bias[tx * TN + n4 * 4];
                o.x = fmaxf(o.x + b4.x, 0.0f);
                o.y = fmaxf(o.y + b4.y, 0.0f);
                o.z = fmaxf(o.z + b4.z, 0.0f);
                o.w = fmaxf(o.w + b4.w, 0.0f);
            }
            if (OB) {
                ushort4 o16;
                o16.x = f2bf(o.x); o16.y = f2bf(o.y);
                o16.z = f2bf(o.z); o16.w = f2bf(o.w);
                *(ushort4*)((unsigned short*)Hv + (size_t)r * OUT + tx * TN + n4 * 4) = o16;
            } else {
                *(float4*)((float*)Hv + (size_t)r * OUT + tx * TN + n4 * 4) = o;
            }
        }
    }
}

// --- F=64 aggregation over bf16 operand, unrolled x4.
// BR: relu(agg+bias). OB: output bf16 (else fp32).
template <bool BR, bool OB>
__global__ void k_agg64_bf(const int* __restrict__ srt, const int* __restrict__ rowoff,
                           const int* __restrict__ counts, const float* __restrict__ dinv,
                           const unsigned short* __restrict__ H, const float* __restrict__ bias,
                           void* __restrict__ Ov, int N) {
    int node = blockIdx.x * (blockDim.x >> 6) + (threadIdx.x >> 6);
    int lane = threadIdx.x & 63;
    if (node >= N) return;
    float dv = dinv[node];
    float acc = bf2f(H[(size_t)node * 64 + lane]) * dv * dv;  // self-loop
    const int* sp = srt + rowoff[node];
    int ce = counts[node];
    int e = 0;
    for (; e + 3 < ce; e += 4) {
        int s0 = sp[e], s1 = sp[e + 1], s2 = sp[e + 2], s3 = sp[e + 3];
        float w0 = dinv[s0] * dv, w1 = dinv[s1] * dv;
        float w2 = dinv[s2] * dv, w3 = dinv[s3] * dv;
        float h0 = bf2f(H[(size_t)s0 * 64 + lane]);
        float h1 = bf2f(H[(size_t)s1 * 64 + lane]);
        float h2 = bf2f(H[(size_t)s2 * 64 + lane]);
        float h3 = bf2f(H[(size_t)s3 * 64 + lane]);
        acc = fmaf(h0, w0, acc);
        acc = fmaf(h1, w1, acc);
        acc = fmaf(h2, w2, acc);
        acc = fmaf(h3, w3, acc);
    }
    for (; e < ce; ++e) {
        int s0 = sp[e];
        acc = fmaf(bf2f(H[(size_t)s0 * 64 + lane]), dinv[s0] * dv, acc);
    }
    if (BR) acc = fmaxf(acc + bias[lane], 0.0f);
    if (OB) ((unsigned short*)Ov)[(size_t)node * 64 + lane] = f2bf(acc);
    else    ((float*)Ov)[(size_t)node * 64 + lane] = acc;
}

// --- pooling (batch sorted): wave-run accumulation ------------------------
__global__ void k_zero_f(float* p, int n) {
    int i = blockIdx.x * blockDim.x + threadIdx.x;
    if (i < n) p[i] = 0.0f;
}

__global__ void k_pool_seg(const float* __restrict__ H, const int* __restrict__ batch,
                           float* __restrict__ sums, float* __restrict__ cnt, int N) {
    int gw = (blockIdx.x * blockDim.x + threadIdx.x) >> 6;
    int lane = threadIdx.x & 63;
    int start = gw * 64;
    if (start >= N) return;
    int end = min(N, start + 64);
    int gcur = batch[start];
    float acc = 0.0f, c = 0.0f;
    for (int i = start; i < end; ++i) {
        int g = batch[i];
        if (g != gcur) {
            atomicAdd(&sums[(size_t)gcur * 64 + lane], acc);
            if (lane == 0) atomicAdd(&cnt[gcur], c);
            acc = 0.0f; c = 0.0f; gcur = g;
        }
        acc += H[(size_t)i * 64 + lane];
        c += 1.0f;
    }
    atomicAdd(&sums[(size_t)gcur * 64 + lane], acc);
    if (lane == 0) atomicAdd(&cnt[gcur], c);
}

// --- head: mean, fc, log_softmax ------------------------------------------
__global__ void k_head(const float* __restrict__ sums, const float* __restrict__ cnt,
                       const float* __restrict__ fcw, const float* __restrict__ fcb,
                       float* __restrict__ out, int G) {
    int g = blockIdx.x * blockDim.x + threadIdx.x;
    if (g >= G) return;
    float inv = 1.0f / fmaxf(cnt[g], 1.0f);
    float l[6];
#pragma unroll
    for (int c = 0; c < 6; ++c) {
        float acc = fcb[c];
        for (int f = 0; f < 64; ++f)
            acc = fmaf(sums[(size_t)g * 64 + f] * inv, fcw[f * 6 + c], acc);
        l[c] = acc;
    }
    float m = l[0];
#pragma unroll
    for (int c = 1; c < 6; ++c) m = fmaxf(m, l[c]);
    float se = 0.0f;
#pragma unroll
    for (int c = 0; c < 6; ++c) se += expf(l[c] - m);
    float lse = m + logf(se);
#pragma unroll
    for (int c = 0; c < 6; ++c) out[(size_t)g * 6 + c] = l[c] - lse;
}

// ---------------------------------------------------------------------------
extern "C" void kernel_launch(void* const* d_in, const int* in_sizes, int n_in,
                              void* d_out, int out_size, void* d_ws, size_t ws_size,
                              hipStream_t stream) {
    const float* x    = (const float*)d_in[0];
    const int*   eidx = (const int*)d_in[1];
    const int*   batch= (const int*)d_in[2];
    const float* W1   = (const float*)d_in[3];
    const float* b1   = (const float*)d_in[4];
    const float* W2   = (const float*)d_in[5];
    const float* b2   = (const float*)d_in[6];
    const float* W3   = (const float*)d_in[7];
    const float* b3   = (const float*)d_in[8];
    const float* fcw  = (const float*)d_in[9];
    const float* fcb  = (const float*)d_in[10];
    float* out = (float*)d_out;

    const int N = in_sizes[2];          // 100000
    const int E = in_sizes[1] / 2;      // 3200000
    const int G = out_size / 6;         // 512
    const int nbuk = (N + 511) >> BUK_SHIFT;  // 196
    const int M = nbuk * NB_BIN;              // 100352

    const int* src = eidx;
    const int* dst = eidx + E;

    float* ws = (float*)d_ws;
    size_t off = 0;
    auto take = [&](size_t n4) {
        float* p = ws + off;
        off += (n4 + 15) & ~(size_t)15;
        return p;
    };
    float* dinv    = take((size_t)N);
    int*   srt     = (int*)take((size_t)E);
    int*   rowoff  = (int*)take((size_t)N);
    int*   counts  = (int*)take((size_t)N);
    int*   histT   = (int*)take((size_t)M);
    int*   scanI   = (int*)take((size_t)M);
    int*   partials= (int*)take(512);
    unsigned short* H16a = (unsigned short*)take((size_t)N * 32);  // N*64 bf16
    unsigned short* H16b = (unsigned short*)take((size_t)N * 32);  // N*64 bf16
    float* A32     = take((size_t)N * 64);
    float* B32     = take((size_t)N * 128);
    float* sums    = take((size_t)G * 64);
    float* cnt     = take((size_t)G);
    (void)ws_size;

    int2* pairs = (int2*)B32;  // alias: B32 first written by GEMM2, after bucketC

    const int B = 256;
    const int NBLK_M = grid_for(M, 256);  // 392

    // --- CSR build (LDS-binned two-level radix) ---
    k_histA<<<NB_BIN, B, 0, stream>>>(dst, histT, E, nbuk);
    k_scan_block_lin<<<NBLK_M, B, 0, stream>>>(histT, scanI, partials, M);
    k_scan_partials<<<1, 512, 0, stream>>>(partials, NBLK_M);
    k_binB<<<NB_BIN, B, 0, stream>>>(src, dst, histT, scanI, partials, pairs, E, nbuk);
    k_bucketC<<<nbuk, B, 0, stream>>>(pairs, histT, scanI, partials, srt, counts,
                                      rowoff, dinv, E, nbuk, N);

    // --- layer 1: h16a = x@W1 (bf16 out); agg+bias+relu -> H16b (bf16) ---
    k_gemm_tile<128, 64, 4, false, true><<<grid_for(N, 64), B, 0, stream>>>(x, W1, nullptr, H16a, N);
    k_agg64_bf<true, true><<<grid_for(N, 4), B, 0, stream>>>(srt, rowoff, counts, dinv, H16a, b1, H16b, N);

    // --- layer 2 (aggregate-first): A32 = A_norm@H16b; B32 = relu(A32@W2+b2) ---
    k_agg64_bf<false, false><<<grid_for(N, 4), B, 0, stream>>>(srt, rowoff, counts, dinv, H16b, nullptr, A32, N);
    k_gemm_tile<64, 128, 8, true, false><<<grid_for(N, 64), B, 0, stream>>>(A32, W2, b2, B32, N);

    // --- layer 3: H16a = B32@W3 (bf16 out); agg+bias+relu -> A32 (fp32) ---
    k_gemm_tile<128, 64, 4, false, true><<<grid_for(N, 64), B, 0, stream>>>(B32, W3, nullptr, H16a, N);
    k_agg64_bf<true, false><<<grid_for(N, 4), B, 0, stream>>>(srt, rowoff, counts, dinv, H16a, b3, A32, N);

    // --- pool + head ---
    k_zero_f<<<grid_for(G * 64, B), B, 0, stream>>>(sums, G * 64);
    k_zero_f<<<grid_for(G, B), B, 0, stream>>>(cnt, G);
    k_pool_seg<<<grid_for((long long)grid_for(N, 64) * 64, B), B, 0, stream>>>(A32, batch, sums, cnt, N);
    k_head<<<grid_for(G, 64), 64, 0, stream>>>(sums, cnt, fcw, fcb, out, G);
}

// Round 10
// 517.947 us; speedup vs baseline: 3.3005x; 1.0502x over previous
//
#include <hip/hip_runtime.h>

// ---------------------------------------------------------------------------
// GCN forward: 3x GCNConv(+relu) -> global_mean_pool -> fc -> log_softmax
// N=100000 nodes, E=3200000 edges, G=512 graphs, feats 128->64->128->64
// R9: aggregation v2 — operand pre-scaled by dinv at the producer
// (edge contribution = plain sum of Hs[src]), and 2 edges gathered per VMEM
// instruction (half-wave per edge, uint = 2 bf16 features, shfl_xor merge).
// CSR build: LDS-binned two-level radix. Layer 2 aggregate-first.
// ---------------------------------------------------------------------------

static inline int grid_for(long long total, int block) {
    return (int)((total + block - 1) / block);
}

#define NB_BIN 512    // binning blocks
#define BUK_SHIFT 9   // 512 nodes per bucket

__device__ __forceinline__ float bflo(unsigned int u) {
    union { unsigned int ui; float f; } c; c.ui = u << 16; return c.f;
}
__device__ __forceinline__ float bfhi(unsigned int u) {
    union { unsigned int ui; float f; } c; c.ui = u & 0xFFFF0000u; return c.f;
}
__device__ __forceinline__ unsigned short f2bf(float f) {
    union { unsigned int ui; float f; } c; c.f = f;
    unsigned int u = c.ui;
    return (unsigned short)((u + 0x7FFFu + ((u >> 16) & 1u)) >> 16);  // RNE
}

// --- pass A: per-(block,bucket) LDS histogram, transposed out --------------
__global__ __launch_bounds__(256) void k_histA(const int* __restrict__ dst,
                                               int* __restrict__ histT,
                                               int E, int nbuk) {
    __shared__ int h[256];
    const int c = blockIdx.x;
    for (int i = threadIdx.x; i < nbuk; i += 256) h[i] = 0;
    __syncthreads();
    const int per = (E + NB_BIN - 1) / NB_BIN;
    const int lo = c * per, hi = min(E, lo + per);
    for (int i = lo + (int)threadIdx.x; i < hi; i += 256)
        atomicAdd(&h[dst[i] >> BUK_SHIFT], 1);
    __syncthreads();
    for (int i = threadIdx.x; i < nbuk; i += 256)
        histT[i * NB_BIN + c] = h[i];
}

// --- linear 2-level scan ---------------------------------------------------
__global__ void k_scan_block_lin(const int* __restrict__ in, int* __restrict__ outI,
                                 int* __restrict__ partials, int M) {
    __shared__ int s[256];
    int tid = threadIdx.x;
    int i = blockIdx.x * 256 + tid;
    int v = (i < M) ? in[i] : 0;
    s[tid] = v;
    __syncthreads();
    for (int off = 1; off < 256; off <<= 1) {
        int t = (tid >= off) ? s[tid - off] : 0;
        __syncthreads();
        s[tid] += t;
        __syncthreads();
    }
    if (i < M) outI[i] = s[tid];  // block-inclusive
    if (tid == 255) partials[blockIdx.x] = s[255];
}

__global__ void k_scan_partials(int* __restrict__ partials, int nblk) {
    __shared__ int s[512];
    int tid = threadIdx.x;
    int v = (tid < nblk) ? partials[tid] : 0;
    s[tid] = v;
    __syncthreads();
    for (int off = 1; off < 512; off <<= 1) {
        int t = (tid >= off) ? s[tid - off] : 0;
        __syncthreads();
        s[tid] += t;
        __syncthreads();
    }
    if (tid < nblk) partials[tid] = s[tid] - v;  // exclusive
}

// --- pass B: bin (src,dst) pairs; per-block LDS cursors --------------------
__global__ __launch_bounds__(256) void k_binB(const int* __restrict__ src,
                                              const int* __restrict__ dst,
                                              const int* __restrict__ histT,
                                              const int* __restrict__ scanI,
                                              const int* __restrict__ partials,
                                              int2* __restrict__ pairs,
                                              int E, int nbuk) {
    __shared__ int cur[256];
    const int c = blockIdx.x;
    for (int b = threadIdx.x; b < nbuk; b += 256) {
        int idx = b * NB_BIN + c;
        cur[b] = scanI[idx] - histT[idx] + partials[idx >> 8];
    }
    __syncthreads();
    const int per = (E + NB_BIN - 1) / NB_BIN;
    const int lo = c * per, hi = min(E, lo + per);
    for (int i = lo + (int)threadIdx.x; i < hi; i += 256) {
        int d = dst[i];
        int pos = atomicAdd(&cur[d >> BUK_SHIFT], 1);
        pairs[pos] = make_int2(src[i], d);
    }
}

// --- pass C: per-bucket counting sort + CSR metadata -----------------------
__global__ __launch_bounds__(256) void k_bucketC(const int2* __restrict__ pairs,
                                                 const int* __restrict__ histT,
                                                 const int* __restrict__ scanI,
                                                 const int* __restrict__ partials,
                                                 int* __restrict__ srt,
                                                 int* __restrict__ counts,
                                                 int* __restrict__ rowoff,
                                                 float* __restrict__ dinv,
                                                 int E, int nbuk, int N) {
    const int b = blockIdx.x;
    const int tid = threadIdx.x;
    __shared__ int h[512];
    __shared__ int loff[512];
    __shared__ int s2[256];

    int idx0 = b * NB_BIN;
    int base = scanI[idx0] - histT[idx0] + partials[idx0 >> 8];
    int end;
    if (b + 1 < nbuk) {
        int idx1 = (b + 1) * NB_BIN;
        end = scanI[idx1] - histT[idx1] + partials[idx1 >> 8];
    } else {
        end = E;
    }

    const int n0 = b << BUK_SHIFT;
    const int nn = min(512, N - n0);

    h[tid] = 0; h[tid + 256] = 0;
    __syncthreads();
    for (int i = base + tid; i < end; i += 256)
        atomicAdd(&h[pairs[i].y & 511], 1);
    __syncthreads();

    int a0 = h[2 * tid], a1 = h[2 * tid + 1];
    s2[tid] = a0 + a1;
    __syncthreads();
    for (int off = 1; off < 256; off <<= 1) {
        int t = (tid >= off) ? s2[tid - off] : 0;
        __syncthreads();
        s2[tid] += t;
        __syncthreads();
    }
    int e2 = s2[tid] - (a0 + a1);
    loff[2 * tid] = e2;
    loff[2 * tid + 1] = e2 + a0;
    __syncthreads();

    for (int i = tid; i < nn; i += 256) {
        int cc = h[i];
        counts[n0 + i] = cc;
        rowoff[n0 + i] = base + loff[i];
        dinv[n0 + i] = rsqrtf((float)cc + 1.0f);
    }
    __syncthreads();
    h[tid] = loff[tid]; h[tid + 256] = loff[tid + 256];
    __syncthreads();
    for (int i = base + tid; i < end; i += 256) {
        int2 p = pairs[i];
        int pos = atomicAdd(&h[p.y & 511], 1);
        srt[base + pos] = p.x;
    }
}

// --- register-blocked tiled GEMM: H[N,OUT] = X[N,IN] @ W[IN,OUT] -----------
// BR: fuse relu(out+bias). OB: output bf16, pre-scaled by scale[row].
template <int IN, int OUT, int TN, bool BR, bool OB>
__global__ __launch_bounds__(256) void k_gemm_tile(const float* __restrict__ X,
                                                   const float* __restrict__ W,
                                                   const float* __restrict__ bias,
                                                   const float* __restrict__ scale,
                                                   void* __restrict__ Hv, int N) {
    constexpr int ROWS = 64;
    constexpr int CT = OUT / TN;
    constexpr int RT = 256 / CT;
    constexpr int TM = ROWS / RT;
    static_assert(CT * RT == 256 && TM * RT == ROWS, "tile mismatch");
    __shared__ float Xs[ROWS][IN];
    __shared__ float Ws[IN][OUT];

    const int tid = threadIdx.x;
    const int row0 = blockIdx.x * ROWS;

    for (int i = tid; i < IN * OUT / 4; i += 256)
        ((float4*)Ws)[i] = ((const float4*)W)[i];
    for (int i = tid; i < ROWS * IN / 4; i += 256) {
        int r = i / (IN / 4), kq = i % (IN / 4);
        float4 v = make_float4(0.f, 0.f, 0.f, 0.f);
        if (row0 + r < N) v = *(const float4*)(X + (size_t)(row0 + r) * IN + kq * 4);
        *(float4*)&Xs[r][kq * 4] = v;
    }
    __syncthreads();

    const int tx = tid % CT;
    const int ty = tid / CT;

    float acc[TM][TN];
#pragma unroll
    for (int m = 0; m < TM; ++m)
#pragma unroll
        for (int n = 0; n < TN; ++n) acc[m][n] = 0.0f;

#pragma unroll 2
    for (int kq = 0; kq < IN / 4; ++kq) {
        float a[TM][4];
#pragma unroll
        for (int m = 0; m < TM; ++m) {
            float4 t = *(const float4*)&Xs[ty * TM + m][kq * 4];
            a[m][0] = t.x; a[m][1] = t.y; a[m][2] = t.z; a[m][3] = t.w;
        }
#pragma unroll
        for (int j = 0; j < 4; ++j) {
            float b[TN];
#pragma unroll
            for (int n4 = 0; n4 < TN / 4; ++n4) {
                float4 t = *(const float4*)&Ws[kq * 4 + j][tx * TN + n4 * 4];
                b[n4 * 4 + 0] = t.x; b[n4 * 4 + 1] = t.y;
                b[n4 * 4 + 2] = t.z; b[n4 * 4 + 3] = t.w;
            }
#pragma unroll
            for (int m = 0; m < TM; ++m)
#pragma unroll
                for (int n = 0; n < TN; ++n)
                    acc[m][n] = fmaf(a[m][j], b[n], acc[m][n]);
        }
    }

#pragma unroll
    for (int m = 0; m < TM; ++m) {
        int r = row0 + ty * TM + m;
        if (r >= N) continue;
        float sc = OB ? scale[r] : 1.0f;
#pragma unroll
        for (int n4 = 0; n4 < TN / 4; ++n4) {
            float4 o = make_float4(acc[m][n4 * 4 + 0], acc[m][n4 * 4 + 1],
                                   acc[m][n4 * 4 + 2], acc[m][n4 * 4 + 3]);
            if (BR) {
                float4 b4 = *(const float4*)&bias[tx * TN + n4 * 4];
                o.x = fmaxf(o.x + b4.x, 0.0f);
                o.y = fmaxf(o.y + b4.y, 0.0f);
                o.z = fmaxf(o.z + b4.z, 0.0f);
                o.w = fmaxf(o.w + b4.w, 0.0f);
            }
            if (OB) {
                ushort4 o16;
                o16.x = f2bf(o.x * sc); o16.y = f2bf(o.y * sc);
                o16.z = f2bf(o.z * sc); o16.w = f2bf(o.w * sc);
                *(ushort4*)((unsigned short*)Hv + (size_t)r * OUT + tx * TN + n4 * 4) = o16;
            } else {
                *(float4*)((float*)Hv + (size_t)r * OUT + tx * TN + n4 * 4) = o;
            }
        }
    }
}

// --- aggregation v2: acc = dv * (Hs[node] + sum_e Hs[src_e]); operand is
// pre-scaled bf16 (Hs = h * dinv). Half-wave per edge, uint = 2 features.
// BR: relu(acc+bias). OB: bf16 out. PS: pre-scale output by dv (for next agg).
template <bool BR, bool OB, bool PS>
__global__ void k_agg64_v2(const int* __restrict__ srt, const int* __restrict__ rowoff,
                           const int* __restrict__ counts, const float* __restrict__ dinv,
                           const unsigned int* __restrict__ Hs, const float* __restrict__ bias,
                           void* __restrict__ Ov, int N) {
    int node = blockIdx.x * (blockDim.x >> 6) + (threadIdx.x >> 6);
    int lane = threadIdx.x & 63;
    int half = lane >> 5, l5 = lane & 31;
    if (node >= N) return;
    float dv = dinv[node];
    const int* sp = srt + rowoff[node];
    int ce = counts[node];

    float ax = 0.0f, ay = 0.0f;
    if (half == 0) {  // self-loop once
        unsigned int u = Hs[(size_t)node * 32 + l5];
        ax = bflo(u); ay = bfhi(u);
    }
    int e = half;
    for (; e + 2 < ce; e += 4) {  // per-half stride 2, unrolled x2
        int s0 = sp[e], s1 = sp[e + 2];
        unsigned int u0 = Hs[(size_t)s0 * 32 + l5];
        unsigned int u1 = Hs[(size_t)s1 * 32 + l5];
        ax += bflo(u0); ay += bfhi(u0);
        ax += bflo(u1); ay += bfhi(u1);
    }
    if (e < ce) {
        unsigned int u0 = Hs[(size_t)sp[e] * 32 + l5];
        ax += bflo(u0); ay += bfhi(u0);
    }
    ax += __shfl_xor(ax, 32, 64);
    ay += __shfl_xor(ay, 32, 64);

    float ox = ax * dv, oy = ay * dv;
    if (BR) {
        float2 b2 = *(const float2*)(bias + 2 * l5);
        ox = fmaxf(ox + b2.x, 0.0f);
        oy = fmaxf(oy + b2.y, 0.0f);
    }
    if (PS) { ox *= dv; oy *= dv; }
    if (half == 0) {
        if (OB) {
            unsigned int o = (unsigned int)f2bf(ox) | ((unsigned int)f2bf(oy) << 16);
            ((unsigned int*)Ov)[(size_t)node * 32 + l5] = o;
        } else {
            ((float2*)Ov)[(size_t)node * 32 + l5] = make_float2(ox, oy);
        }
    }
}

// --- pooling (batch sorted): wave-run accumulation ------------------------
__global__ void k_zero_f(float* p, int n) {
    int i = blockIdx.x * blockDim.x + threadIdx.x;
    if (i < n) p[i] = 0.0f;
}

__global__ void k_pool_seg(const float* __restrict__ H, const int* __restrict__ batch,
                           float* __restrict__ sums, float* __restrict__ cnt, int N) {
    int gw = (blockIdx.x * blockDim.x + threadIdx.x) >> 6;
    int lane = threadIdx.x & 63;
    int start = gw * 64;
    if (start >= N) return;
    int end = min(N, start + 64);
    int gcur = batch[start];
    float acc = 0.0f, c = 0.0f;
    for (int i = start; i < end; ++i) {
        int g = batch[i];
        if (g != gcur) {
            atomicAdd(&sums[(size_t)gcur * 64 + lane], acc);
            if (lane == 0) atomicAdd(&cnt[gcur], c);
            acc = 0.0f; c = 0.0f; gcur = g;
        }
        acc += H[(size_t)i * 64 + lane];
        c += 1.0f;
    }
    atomicAdd(&sums[(size_t)gcur * 64 + lane], acc);
    if (lane == 0) atomicAdd(&cnt[gcur], c);
}

// --- head: mean, fc, log_softmax ------------------------------------------
__global__ void k_head(const float* __restrict__ sums, const float* __restrict__ cnt,
                       const float* __restrict__ fcw, const float* __restrict__ fcb,
                       float* __restrict__ out, int G) {
    int g = blockIdx.x * blockDim.x + threadIdx.x;
    if (g >= G) return;
    float inv = 1.0f / fmaxf(cnt[g], 1.0f);
    float l[6];
#pragma unroll
    for (int c = 0; c < 6; ++c) {
        float acc = fcb[c];
        for (int f = 0; f < 64; ++f)
            acc = fmaf(sums[(size_t)g * 64 + f] * inv, fcw[f * 6 + c], acc);
        l[c] = acc;
    }
    float m = l[0];
#pragma unroll
    for (int c = 1; c < 6; ++c) m = fmaxf(m, l[c]);
    float se = 0.0f;
#pragma unroll
    for (int c = 0; c < 6; ++c) se += expf(l[c] - m);
    float lse = m + logf(se);
#pragma unroll
    for (int c = 0; c < 6; ++c) out[(size_t)g * 6 + c] = l[c] - lse;
}

// ---------------------------------------------------------------------------
extern "C" void kernel_launch(void* const* d_in, const int* in_sizes, int n_in,
                              void* d_out, int out_size, void* d_ws, size_t ws_size,
                              hipStream_t stream) {
    const float* x    = (const float*)d_in[0];
    const int*   eidx = (const int*)d_in[1];
    const int*   batch= (const int*)d_in[2];
    const float* W1   = (const float*)d_in[3];
    const float* b1   = (const float*)d_in[4];
    const float* W2   = (const float*)d_in[5];
    const float* b2   = (const float*)d_in[6];
    const float* W3   = (const float*)d_in[7];
    const float* b3   = (const float*)d_in[8];
    const float* fcw  = (const float*)d_in[9];
    const float* fcb  = (const float*)d_in[10];
    float* out = (float*)d_out;

    const int N = in_sizes[2];          // 100000
    const int E = in_sizes[1] / 2;      // 3200000
    const int G = out_size / 6;         // 512
    const int nbuk = (N + 511) >> BUK_SHIFT;  // 196
    const int M = nbuk * NB_BIN;              // 100352

    const int* src = eidx;
    const int* dst = eidx + E;

    float* ws = (float*)d_ws;
    size_t off = 0;
    auto take = [&](size_t n4) {
        float* p = ws + off;
        off += (n4 + 15) & ~(size_t)15;
        return p;
    };
    float* dinv    = take((size_t)N);
    int*   srt     = (int*)take((size_t)E);
    int*   rowoff  = (int*)take((size_t)N);
    int*   counts  = (int*)take((size_t)N);
    int*   histT   = (int*)take((size_t)M);
    int*   scanI   = (int*)take((size_t)M);
    int*   partials= (int*)take(512);
    unsigned int* H16a = (unsigned int*)take((size_t)N * 32);  // N*64 bf16
    unsigned int* H16b = (unsigned int*)take((size_t)N * 32);  // N*64 bf16
    float* A32     = take((size_t)N * 64);
    float* B32     = take((size_t)N * 128);
    float* sums    = take((size_t)G * 64);
    float* cnt     = take((size_t)G);
    (void)ws_size;

    int2* pairs = (int2*)B32;  // alias: B32 first written by GEMM2, after bucketC

    const int B = 256;
    const int NBLK_M = grid_for(M, 256);  // 392

    // --- CSR build (LDS-binned two-level radix) ---
    k_histA<<<NB_BIN, B, 0, stream>>>(dst, histT, E, nbuk);
    k_scan_block_lin<<<NBLK_M, B, 0, stream>>>(histT, scanI, partials, M);
    k_scan_partials<<<1, 512, 0, stream>>>(partials, NBLK_M);
    k_binB<<<NB_BIN, B, 0, stream>>>(src, dst, histT, scanI, partials, pairs, E, nbuk);
    k_bucketC<<<nbuk, B, 0, stream>>>(pairs, histT, scanI, partials, srt, counts,
                                      rowoff, dinv, E, nbuk, N);

    // --- layer 1: H16a = (x@W1)*dinv (bf16); agg -> H16b = relu(.)+b1 scaled ---
    k_gemm_tile<128, 64, 4, false, true><<<grid_for(N, 64), B, 0, stream>>>(x, W1, nullptr, dinv, H16a, N);
    k_agg64_v2<true, true, true><<<grid_for(N, 4), B, 0, stream>>>(srt, rowoff, counts, dinv, H16a, b1, H16b, N);

    // --- layer 2 (aggregate-first): A32 = A_norm-apply on H16b (fp32);
    //     B32 = relu(A32@W2 + b2) [N,128] ---
    k_agg64_v2<false, false, false><<<grid_for(N, 4), B, 0, stream>>>(srt, rowoff, counts, dinv, H16b, nullptr, A32, N);
    k_gemm_tile<64, 128, 8, true, false><<<grid_for(N, 64), B, 0, stream>>>(A32, W2, b2, nullptr, B32, N);

    // --- layer 3: H16a = (B32@W3)*dinv (bf16); agg -> A32 = relu(.+b3) fp32 ---
    k_gemm_tile<128, 64, 4, false, true><<<grid_for(N, 64), B, 0, stream>>>(B32, W3, nullptr, dinv, H16a, N);
    k_agg64_v2<true, false, false><<<grid_for(N, 4), B, 0, stream>>>(srt, rowoff, counts, dinv, H16a, b3, A32, N);

    // --- pool + head ---
    k_zero_f<<<grid_for(G * 64, B), B, 0, stream>>>(sums, G * 64);
    k_zero_f<<<grid_for(G, B), B, 0, stream>>>(cnt, G);
    k_pool_seg<<<grid_for((long long)grid_for(N, 64) * 64, B), B, 0, stream>>>(A32, batch, sums, cnt, N);
    k_head<<<grid_for(G, 64), 64, 0, stream>>>(sums, cnt, fcw, fcb, out, G);
}

// Round 11
// 421.132 us; speedup vs baseline: 4.0593x; 1.2299x over previous
//
#include <hip/hip_runtime.h>

// ---------------------------------------------------------------------------
// GCN forward: 3x GCNConv(+relu) -> global_mean_pool -> fc -> log_softmax
// N=100000 nodes, E=3200000 edges, G=512 graphs, feats 128->64->128->64
// R10: aggregation v3 — quarter-wave (16 lanes) per edge, uint2 = 4 bf16
// features per lane (one 128B row per gather), 4 edges per instruction,
// unrolled x4 (4 gathers in flight). Operand pre-scaled by dinv (edge
// contribution = plain sum). shfl_xor(16)+shfl_xor(32) reduce.
// CSR build: LDS-binned two-level radix. Layer 2 aggregate-first.
// ---------------------------------------------------------------------------

static inline int grid_for(long long total, int block) {
    return (int)((total + block - 1) / block);
}

#define NB_BIN 512    // binning blocks
#define BUK_SHIFT 9   // 512 nodes per bucket

__device__ __forceinline__ float bflo(unsigned int u) {
    union { unsigned int ui; float f; } c; c.ui = u << 16; return c.f;
}
__device__ __forceinline__ float bfhi(unsigned int u) {
    union { unsigned int ui; float f; } c; c.ui = u & 0xFFFF0000u; return c.f;
}
__device__ __forceinline__ unsigned short f2bf(float f) {
    union { unsigned int ui; float f; } c; c.f = f;
    unsigned int u = c.ui;
    return (unsigned short)((u + 0x7FFFu + ((u >> 16) & 1u)) >> 16);  // RNE
}

// --- pass A: per-(block,bucket) LDS histogram, transposed out --------------
__global__ __launch_bounds__(256) void k_histA(const int* __restrict__ dst,
                                               int* __restrict__ histT,
                                               int E, int nbuk) {
    __shared__ int h[256];
    const int c = blockIdx.x;
    for (int i = threadIdx.x; i < nbuk; i += 256) h[i] = 0;
    __syncthreads();
    const int per = (E + NB_BIN - 1) / NB_BIN;
    const int lo = c * per, hi = min(E, lo + per);
    for (int i = lo + (int)threadIdx.x; i < hi; i += 256)
        atomicAdd(&h[dst[i] >> BUK_SHIFT], 1);
    __syncthreads();
    for (int i = threadIdx.x; i < nbuk; i += 256)
        histT[i * NB_BIN + c] = h[i];
}

// --- linear 2-level scan ---------------------------------------------------
__global__ void k_scan_block_lin(const int* __restrict__ in, int* __restrict__ outI,
                                 int* __restrict__ partials, int M) {
    __shared__ int s[256];
    int tid = threadIdx.x;
    int i = blockIdx.x * 256 + tid;
    int v = (i < M) ? in[i] : 0;
    s[tid] = v;
    __syncthreads();
    for (int off = 1; off < 256; off <<= 1) {
        int t = (tid >= off) ? s[tid - off] : 0;
        __syncthreads();
        s[tid] += t;
        __syncthreads();
    }
    if (i < M) outI[i] = s[tid];  // block-inclusive
    if (tid == 255) partials[blockIdx.x] = s[255];
}

__global__ void k_scan_partials(int* __restrict__ partials, int nblk) {
    __shared__ int s[512];
    int tid = threadIdx.x;
    int v = (tid < nblk) ? partials[tid] : 0;
    s[tid] = v;
    __syncthreads();
    for (int off = 1; off < 512; off <<= 1) {
        int t = (tid >= off) ? s[tid - off] : 0;
        __syncthreads();
        s[tid] += t;
        __syncthreads();
    }
    if (tid < nblk) partials[tid] = s[tid] - v;  // exclusive
}

// --- pass B: bin (src,dst) pairs; per-block LDS cursors --------------------
__global__ __launch_bounds__(256) void k_binB(const int* __restrict__ src,
                                              const int* __restrict__ dst,
                                              const int* __restrict__ histT,
                                              const int* __restrict__ scanI,
                                              const int* __restrict__ partials,
                                              int2* __restrict__ pairs,
                                              int E, int nbuk) {
    __shared__ int cur[256];
    const int c = blockIdx.x;
    for (int b = threadIdx.x; b < nbuk; b += 256) {
        int idx = b * NB_BIN + c;
        cur[b] = scanI[idx] - histT[idx] + partials[idx >> 8];
    }
    __syncthreads();
    const int per = (E + NB_BIN - 1) / NB_BIN;
    const int lo = c * per, hi = min(E, lo + per);
    for (int i = lo + (int)threadIdx.x; i < hi; i += 256) {
        int d = dst[i];
        int pos = atomicAdd(&cur[d >> BUK_SHIFT], 1);
        pairs[pos] = make_int2(src[i], d);
    }
}

// --- pass C: per-bucket counting sort + CSR metadata -----------------------
__global__ __launch_bounds__(256) void k_bucketC(const int2* __restrict__ pairs,
                                                 const int* __restrict__ histT,
                                                 const int* __restrict__ scanI,
                                                 const int* __restrict__ partials,
                                                 int* __restrict__ srt,
                                                 int* __restrict__ counts,
                                                 int* __restrict__ rowoff,
                                                 float* __restrict__ dinv,
                                                 int E, int nbuk, int N) {
    const int b = blockIdx.x;
    const int tid = threadIdx.x;
    __shared__ int h[512];
    __shared__ int loff[512];
    __shared__ int s2[256];

    int idx0 = b * NB_BIN;
    int base = scanI[idx0] - histT[idx0] + partials[idx0 >> 8];
    int end;
    if (b + 1 < nbuk) {
        int idx1 = (b + 1) * NB_BIN;
        end = scanI[idx1] - histT[idx1] + partials[idx1 >> 8];
    } else {
        end = E;
    }

    const int n0 = b << BUK_SHIFT;
    const int nn = min(512, N - n0);

    h[tid] = 0; h[tid + 256] = 0;
    __syncthreads();
    for (int i = base + tid; i < end; i += 256)
        atomicAdd(&h[pairs[i].y & 511], 1);
    __syncthreads();

    int a0 = h[2 * tid], a1 = h[2 * tid + 1];
    s2[tid] = a0 + a1;
    __syncthreads();
    for (int off = 1; off < 256; off <<= 1) {
        int t = (tid >= off) ? s2[tid - off] : 0;
        __syncthreads();
        s2[tid] += t;
        __syncthreads();
    }
    int e2 = s2[tid] - (a0 + a1);
    loff[2 * tid] = e2;
    loff[2 * tid + 1] = e2 + a0;
    __syncthreads();

    for (int i = tid; i < nn; i += 256) {
        int cc = h[i];
        counts[n0 + i] = cc;
        rowoff[n0 + i] = base + loff[i];
        dinv[n0 + i] = rsqrtf((float)cc + 1.0f);
    }
    __syncthreads();
    h[tid] = loff[tid]; h[tid + 256] = loff[tid + 256];
    __syncthreads();
    for (int i = base + tid; i < end; i += 256) {
        int2 p = pairs[i];
        int pos = atomicAdd(&h[p.y & 511], 1);
        srt[base + pos] = p.x;
    }
}

// --- register-blocked tiled GEMM: H[N,OUT] = X[N,IN] @ W[IN,OUT] -----------
// BR: fuse relu(out+bias). OB: output bf16, pre-scaled by scale[row].
template <int IN, int OUT, int TN, bool BR, bool OB>
__global__ __launch_bounds__(256) void k_gemm_tile(const float* __restrict__ X,
                                                   const float* __restrict__ W,
                                                   const float* __restrict__ bias,
                                                   const float* __restrict__ scale,
                                                   void* __restrict__ Hv, int N) {
    constexpr int ROWS = 64;
    constexpr int CT = OUT / TN;
    constexpr int RT = 256 / CT;
    constexpr int TM = ROWS / RT;
    static_assert(CT * RT == 256 && TM * RT == ROWS, "tile mismatch");
    __shared__ float Xs[ROWS][IN];
    __shared__ float Ws[IN][OUT];

    const int tid = threadIdx.x;
    const int row0 = blockIdx.x * ROWS;

    for (int i = tid; i < IN * OUT / 4; i += 256)
        ((float4*)Ws)[i] = ((const float4*)W)[i];
    for (int i = tid; i < ROWS * IN / 4; i += 256) {
        int r = i / (IN / 4), kq = i % (IN / 4);
        float4 v = make_float4(0.f, 0.f, 0.f, 0.f);
        if (row0 + r < N) v = *(const float4*)(X + (size_t)(row0 + r) * IN + kq * 4);
        *(float4*)&Xs[r][kq * 4] = v;
    }
    __syncthreads();

    const int tx = tid % CT;
    const int ty = tid / CT;

    float acc[TM][TN];
#pragma unroll
    for (int m = 0; m < TM; ++m)
#pragma unroll
        for (int n = 0; n < TN; ++n) acc[m][n] = 0.0f;

#pragma unroll 2
    for (int kq = 0; kq < IN / 4; ++kq) {
        float a[TM][4];
#pragma unroll
        for (int m = 0; m < TM; ++m) {
            float4 t = *(const float4*)&Xs[ty * TM + m][kq * 4];
            a[m][0] = t.x; a[m][1] = t.y; a[m][2] = t.z; a[m][3] = t.w;
        }
#pragma unroll
        for (int j = 0; j < 4; ++j) {
            float b[TN];
#pragma unroll
            for (int n4 = 0; n4 < TN / 4; ++n4) {
                float4 t = *(const float4*)&Ws[kq * 4 + j][tx * TN + n4 * 4];
                b[n4 * 4 + 0] = t.x; b[n4 * 4 + 1] = t.y;
                b[n4 * 4 + 2] = t.z; b[n4 * 4 + 3] = t.w;
            }
#pragma unroll
            for (int m = 0; m < TM; ++m)
#pragma unroll
                for (int n = 0; n < TN; ++n)
                    acc[m][n] = fmaf(a[m][j], b[n], acc[m][n]);
        }
    }

#pragma unroll
    for (int m = 0; m < TM; ++m) {
        int r = row0 + ty * TM + m;
        if (r >= N) continue;
        float sc = OB ? scale[r] : 1.0f;
#pragma unroll
        for (int n4 = 0; n4 < TN / 4; ++n4) {
            float4 o = make_float4(acc[m][n4 * 4 + 0], acc[m][n4 * 4 + 1],
                                   acc[m][n4 * 4 + 2], acc[m][n4 * 4 + 3]);
            if (BR) {
                float4 b4 = *(const float4*)&bias[tx * TN + n4 * 4];
                o.x = fmaxf(o.x + b4.x, 0.0f);
                o.y = fmaxf(o.y + b4.y, 0.0f);
                o.z = fmaxf(o.z + b4.z, 0.0f);
                o.w = fmaxf(o.w + b4.w, 0.0f);
            }
            if (OB) {
                ushort4 o16;
                o16.x = f2bf(o.x * sc); o16.y = f2bf(o.y * sc);
                o16.z = f2bf(o.z * sc); o16.w = f2bf(o.w * sc);
                *(ushort4*)((unsigned short*)Hv + (size_t)r * OUT + tx * TN + n4 * 4) = o16;
            } else {
                *(float4*)((float*)Hv + (size_t)r * OUT + tx * TN + n4 * 4) = o;
            }
        }
    }
}

// --- aggregation v3: quarter-wave per edge, uint2 (4 bf16) per lane.
// acc = dv * (Hs[node] + sum_e Hs[src_e]);  Hs pre-scaled by dinv.
// BR: relu(acc+bias). OB: bf16 out. PS: pre-scale output by dv.
template <bool BR, bool OB, bool PS>
__global__ void k_agg64_v3(const int* __restrict__ srt, const int* __restrict__ rowoff,
                           const int* __restrict__ counts, const float* __restrict__ dinv,
                           const uint2* __restrict__ Hs, const float* __restrict__ bias,
                           void* __restrict__ Ov, int N) {
    int node = blockIdx.x * (blockDim.x >> 6) + (threadIdx.x >> 6);
    int lane = threadIdx.x & 63;
    int q = lane >> 4, l4 = lane & 15;
    if (node >= N) return;
    float dv = dinv[node];
    const int* sp = srt + rowoff[node];
    int ce = counts[node];

    float a0 = 0.f, a1 = 0.f, a2 = 0.f, a3 = 0.f;
    if (q == 0) {  // self-loop once
        uint2 u = Hs[(size_t)node * 16 + l4];
        a0 = bflo(u.x); a1 = bfhi(u.x); a2 = bflo(u.y); a3 = bfhi(u.y);
    }
    int e = q;
    for (; e + 12 < ce; e += 16) {  // 4 gathers in flight per wave-quarter
        int s0 = sp[e], s1 = sp[e + 4], s2 = sp[e + 8], s3 = sp[e + 12];
        uint2 u0 = Hs[(size_t)s0 * 16 + l4];
        uint2 u1 = Hs[(size_t)s1 * 16 + l4];
        uint2 u2 = Hs[(size_t)s2 * 16 + l4];
        uint2 u3 = Hs[(size_t)s3 * 16 + l4];
        a0 += bflo(u0.x); a1 += bfhi(u0.x); a2 += bflo(u0.y); a3 += bfhi(u0.y);
        a0 += bflo(u1.x); a1 += bfhi(u1.x); a2 += bflo(u1.y); a3 += bfhi(u1.y);
        a0 += bflo(u2.x); a1 += bfhi(u2.x); a2 += bflo(u2.y); a3 += bfhi(u2.y);
        a0 += bflo(u3.x); a1 += bfhi(u3.x); a2 += bflo(u3.y); a3 += bfhi(u3.y);
    }
    for (; e < ce; e += 4) {
        uint2 u = Hs[(size_t)sp[e] * 16 + l4];
        a0 += bflo(u.x); a1 += bfhi(u.x); a2 += bflo(u.y); a3 += bfhi(u.y);
    }
    a0 += __shfl_xor(a0, 16, 64); a0 += __shfl_xor(a0, 32, 64);
    a1 += __shfl_xor(a1, 16, 64); a1 += __shfl_xor(a1, 32, 64);
    a2 += __shfl_xor(a2, 16, 64); a2 += __shfl_xor(a2, 32, 64);
    a3 += __shfl_xor(a3, 16, 64); a3 += __shfl_xor(a3, 32, 64);

    float o0 = a0 * dv, o1 = a1 * dv, o2 = a2 * dv, o3 = a3 * dv;
    if (BR) {
        float4 b4 = *(const float4*)(bias + 4 * l4);
        o0 = fmaxf(o0 + b4.x, 0.0f);
        o1 = fmaxf(o1 + b4.y, 0.0f);
        o2 = fmaxf(o2 + b4.z, 0.0f);
        o3 = fmaxf(o3 + b4.w, 0.0f);
    }
    if (PS) { o0 *= dv; o1 *= dv; o2 *= dv; o3 *= dv; }
    if (q == 0) {
        if (OB) {
            uint2 o;
            o.x = (unsigned int)f2bf(o0) | ((unsigned int)f2bf(o1) << 16);
            o.y = (unsigned int)f2bf(o2) | ((unsigned int)f2bf(o3) << 16);
            ((uint2*)Ov)[(size_t)node * 16 + l4] = o;
        } else {
            ((float4*)Ov)[(size_t)node * 16 + l4] = make_float4(o0, o1, o2, o3);
        }
    }
}

// --- pooling (batch sorted): wave-run accumulation ------------------------
__global__ void k_zero_f(float* p, int n) {
    int i = blockIdx.x * blockDim.x + threadIdx.x;
    if (i < n) p[i] = 0.0f;
}

__global__ void k_pool_seg(const float* __restrict__ H, const int* __restrict__ batch,
                           float* __restrict__ sums, float* __restrict__ cnt, int N) {
    int gw = (blockIdx.x * blockDim.x + threadIdx.x) >> 6;
    int lane = threadIdx.x & 63;
    int start = gw * 64;
    if (start >= N) return;
    int end = min(N, start + 64);
    int gcur = batch[start];
    float acc = 0.0f, c = 0.0f;
    for (int i = start; i < end; ++i) {
        int g = batch[i];
        if (g != gcur) {
            atomicAdd(&sums[(size_t)gcur * 64 + lane], acc);
            if (lane == 0) atomicAdd(&cnt[gcur], c);
            acc = 0.0f; c = 0.0f; gcur = g;
        }
        acc += H[(size_t)i * 64 + lane];
        c += 1.0f;
    }
    atomicAdd(&sums[(size_t)gcur * 64 + lane], acc);
    if (lane == 0) atomicAdd(&cnt[gcur], c);
}

// --- head: mean, fc, log_softmax ------------------------------------------
__global__ void k_head(const float* __restrict__ sums, const float* __restrict__ cnt,
                       const float* __restrict__ fcw, const float* __restrict__ fcb,
                       float* __restrict__ out, int G) {
    int g = blockIdx.x * blockDim.x + threadIdx.x;
    if (g >= G) return;
    float inv = 1.0f / fmaxf(cnt[g], 1.0f);
    float l[6];
#pragma unroll
    for (int c = 0; c < 6; ++c) {
        float acc = fcb[c];
        for (int f = 0; f < 64; ++f)
            acc = fmaf(sums[(size_t)g * 64 + f] * inv, fcw[f * 6 + c], acc);
        l[c] = acc;
    }
    float m = l[0];
#pragma unroll
    for (int c = 1; c < 6; ++c) m = fmaxf(m, l[c]);
    float se = 0.0f;
#pragma unroll
    for (int c = 0; c < 6; ++c) se += expf(l[c] - m);
    float lse = m + logf(se);
#pragma unroll
    for (int c = 0; c < 6; ++c) out[(size_t)g * 6 + c] = l[c] - lse;
}

// ---------------------------------------------------------------------------
extern "C" void kernel_launch(void* const* d_in, const int* in_sizes, int n_in,
                              void* d_out, int out_size, void* d_ws, size_t ws_size,
                              hipStream_t stream) {
    const float* x    = (const float*)d_in[0];
    const int*   eidx = (const int*)d_in[1];
    const int*   batch= (const int*)d_in[2];
    const float* W1   = (const float*)d_in[3];
    const float* b1   = (const float*)d_in[4];
    const float* W2   = (const float*)d_in[5];
    const float* b2   = (const float*)d_in[6];
    const float* W3   = (const float*)d_in[7];
    const float* b3   = (const float*)d_in[8];
    const float* fcw  = (const float*)d_in[9];
    const float* fcb  = (const float*)d_in[10];
    float* out = (float*)d_out;

    const int N = in_sizes[2];          // 100000
    const int E = in_sizes[1] / 2;      // 3200000
    const int G = out_size / 6;         // 512
    const int nbuk = (N + 511) >> BUK_SHIFT;  // 196
    const int M = nbuk * NB_BIN;              // 100352

    const int* src = eidx;
    const int* dst = eidx + E;

    float* ws = (float*)d_ws;
    size_t off = 0;
    auto take = [&](size_t n4) {
        float* p = ws + off;
        off += (n4 + 15) & ~(size_t)15;
        return p;
    };
    float* dinv    = take((size_t)N);
    int*   srt     = (int*)take((size_t)E);
    int*   rowoff  = (int*)take((size_t)N);
    int*   counts  = (int*)take((size_t)N);
    int*   histT   = (int*)take((size_t)M);
    int*   scanI   = (int*)take((size_t)M);
    int*   partials= (int*)take(512);
    uint2* H16a    = (uint2*)take((size_t)N * 32);  // N*64 bf16
    uint2* H16b    = (uint2*)take((size_t)N * 32);  // N*64 bf16
    float* A32     = take((size_t)N * 64);
    float* B32     = take((size_t)N * 128);
    float* sums    = take((size_t)G * 64);
    float* cnt     = take((size_t)G);
    (void)ws_size;

    int2* pairs = (int2*)B32;  // alias: B32 first written by GEMM2, after bucketC

    const int B = 256;
    const int NBLK_M = grid_for(M, 256);  // 392

    // --- CSR build (LDS-binned two-level radix) ---
    k_histA<<<NB_BIN, B, 0, stream>>>(dst, histT, E, nbuk);
    k_scan_block_lin<<<NBLK_M, B, 0, stream>>>(histT, scanI, partials, M);
    k_scan_partials<<<1, 512, 0, stream>>>(partials, NBLK_M);
    k_binB<<<NB_BIN, B, 0, stream>>>(src, dst, histT, scanI, partials, pairs, E, nbuk);
    k_bucketC<<<nbuk, B, 0, stream>>>(pairs, histT, scanI, partials, srt, counts,
                                      rowoff, dinv, E, nbuk, N);

    // --- layer 1: H16a = (x@W1)*dinv (bf16); agg -> H16b (bf16, rescaled) ---
    k_gemm_tile<128, 64, 4, false, true><<<grid_for(N, 64), B, 0, stream>>>(x, W1, nullptr, dinv, H16a, N);
    k_agg64_v3<true, true, true><<<grid_for(N, 4), B, 0, stream>>>(srt, rowoff, counts, dinv, H16a, b1, H16b, N);

    // --- layer 2 (aggregate-first): A32 = A_norm-apply on H16b (fp32);
    //     B32 = relu(A32@W2 + b2) [N,128] ---
    k_agg64_v3<false, false, false><<<grid_for(N, 4), B, 0, stream>>>(srt, rowoff, counts, dinv, H16b, nullptr, A32, N);
    k_gemm_tile<64, 128, 8, true, false><<<grid_for(N, 64), B, 0, stream>>>(A32, W2, b2, nullptr, B32, N);

    // --- layer 3: H16a = (B32@W3)*dinv (bf16); agg -> A32 = relu(.+b3) fp32 ---
    k_gemm_tile<128, 64, 4, false, true><<<grid_for(N, 64), B, 0, stream>>>(B32, W3, nullptr, dinv, H16a, N);
    k_agg64_v3<true, false, false><<<grid_for(N, 4), B, 0, stream>>>(srt, rowoff, counts, dinv, H16a, b3, A32, N);

    // --- pool + head ---
    k_zero_f<<<grid_for(G * 64, B), B, 0, stream>>>(sums, G * 64);
    k_zero_f<<<grid_for(G, B), B, 0, stream>>>(cnt, G);
    k_pool_seg<<<grid_for((long long)grid_for(N, 64) * 64, B), B, 0, stream>>>(A32, batch, sums, cnt, N);
    k_head<<<grid_for(G, 64), 64, 0, stream>>>(sums, cnt, fcw, fcb, out, G);
}